// Round 10
// baseline (428.401 us; speedup 1.0000x reference)
//
#include <hip/hip_runtime.h>
#include <hip/hip_bf16.h>

#define DEV __device__ __forceinline__
using bf16 = __hip_bfloat16;
using u16 = unsigned short;
using u64 = unsigned long long;

static constexpr int B_ = 2, N_ = 4096, M_ = 512, K_ = 50;
static constexpr int BN = B_ * N_;   // 8192 points
static constexpr int BM = B_ * M_;   // 1024 grid points
static constexpr float EPS_ = 1e-5f;

DEV float lrelu(float z) { return z < 0.f ? 0.2f * z : z; }
DEV int clampi(int v, int hi) { return ((unsigned)v < (unsigned)hi) ? v : 0; }

// bf16 split helpers (RNE, matches __float2bfloat16 for normals)
DEV u16 f2bfu(float f) {
    unsigned u = __float_as_uint(f);
    return (u16)((u + 0x7fffu + ((u >> 16) & 1u)) >> 16);
}
DEV float bfu2f(u16 h) { return __uint_as_float((unsigned)h << 16); }
// packed f32x2 -> bf16x2; hw round mode; 1-ulp diffs absorbed by lo plane.
DEV unsigned cvtpk(float a, float b) {
    unsigned r;
    asm("v_cvt_pk_bf16_f32 %0, %1, %2" : "=v"(r) : "v"(a), "v"(b));
    return r;
}

typedef short bf8v __attribute__((ext_vector_type(8)));   // 8 bf16 (4 VGPRs)
typedef float f4v __attribute__((ext_vector_type(4)));    // MFMA C/D

// ---------------------------------------------------------------- dtype detect
__global__ void k_detect(const unsigned short* __restrict__ xw, int* __restrict__ flag) {
    int t = threadIdx.x;
    int cnt = 0;
    for (int i = t; i < 4096; i += 256) {
        int e = (xw[i] >> 7) & 0xFF;
        if (e >= 100 && e <= 140) cnt++;
    }
    __shared__ int sh[256];
    sh[t] = cnt;
    __syncthreads();
    for (int s = 128; s; s >>= 1) { if (t < s) sh[t] += sh[t + s]; __syncthreads(); }
    if (t == 0) *flag = (sh[0] >= 3300) ? 1 : 0;
}

// ---------------------------------------------------------------- convert params to f32
struct CvtDesc { const void* src; float* dst; int n; };
struct CvtArgs { CvtDesc d[25]; };
__global__ void k_convert(CvtArgs a, const int* __restrict__ flag) {
    CvtDesc dd = a.d[blockIdx.y];
    int i = blockIdx.x * 256 + threadIdx.x;
    if (i >= dd.n) return;
    float v = (*flag) ? __bfloat162float(((const bf16*)dd.src)[i])
                      : ((const float*)dd.src)[i];
    dd.dst[i] = v;
}

// ---------------------------------------------------------------- transposed weight copies
struct CvtT { const void* src; float* dst; int O; int C; int stride; int off; };
struct CvtTArgs { CvtT d[6]; };
__global__ void k_convT(CvtTArgs a, const int* __restrict__ flag) {
    CvtT dd = a.d[blockIdx.y];
    int idx = blockIdx.x * 256 + threadIdx.x;
    if (idx >= dd.O * dd.C) return;
    int c = idx / dd.O, o = idx % dd.O;
    int si = o * dd.stride + dd.off + c;
    float v = (*flag) ? __bfloat162float(((const bf16*)dd.src)[si])
                      : ((const float*)dd.src)[si];
    dd.dst[idx] = v;   // dst[c*O + o]
}

// ---------------------------------------------------------------- W2/W4 bf16-split MFMA B-fragments
__global__ void k_wfrag(const float* __restrict__ Wa, const float* __restrict__ Wb,
                        u16* __restrict__ fa, u16* __restrict__ fb) {
    const float* W = blockIdx.y ? Wb : Wa;
    u16* f = blockIdx.y ? fb : fa;
    int t = blockIdx.x * 256 + threadIdx.x;   // 0..4095
    int j = t & 7, l = (t >> 3) & 63, s = (t >> 9) & 1, n = (t >> 10) & 3;
    int o = n * 16 + (l & 15);
    int c = s * 32 + (l >> 4) * 8 + j;
    float v = W[o * 64 + c];
    u16 hi = f2bfu(v);
    u16 lo = f2bfu(v - bfu2f(hi));
    f[t] = hi;
    f[4096 + t] = lo;
}

// ---------------------------------------------------------------- W7 (192-col part) bf16-split MFMA B-fragments
__global__ void k_wfrag7(const float* __restrict__ W7vt, u16* __restrict__ f) {
    int t = blockIdx.x * 256 + threadIdx.x;   // 0..24575
    int j = t & 7, l = (t >> 3) & 63;
    int rest = t >> 9;                        // 0..47
    int s = rest % 6, ot = rest / 6;
    int o = ot * 16 + (l & 15);
    int c = s * 32 + (l >> 4) * 8 + j;
    float v = W7vt[c * 128 + o];
    u16 hi = f2bfu(v);
    u16 lo = f2bfu(v - bfu2f(hi));
    f[t] = hi;
    f[24576 + t] = lo;
}

// ---------------------------------------------------------------- ubuf: a*Pg + s per stage (pass1 Z-build prefold)
__global__ void k_ubuf(const float* __restrict__ Pg, const float* __restrict__ prm,
                       float* __restrict__ ub) {
    int t = blockIdx.x * 256 + threadIdx.x;   // BM*64
    int c = t & 63;
    ub[t] = fmaf(prm[c], Pg[t], prm[64 + c]);
}

// ---------------------------------------------------------------- transpose (flat regrid; + gn for grid)
DEV float rdval(const void* p, int i, int isbf) {
    return isbf ? __bfloat162float(((const bf16*)p)[i]) : ((const float*)p)[i];
}
__global__ void k_transpose(const void* __restrict__ x, const void* __restrict__ xg,
                            const int* __restrict__ flag,
                            float* __restrict__ xt, float* __restrict__ gt,
                            float* __restrict__ gT3, float* __restrict__ gn) {
    int isbf = *flag;
    int idx = blockIdx.x * 256 + threadIdx.x;
    if (idx < BN * 3) {
        int c = idx / BN, i = idx % BN;
        int b = i / N_, n = i % N_;
        xt[i * 3 + c] = rdval(x, (b * 3 + c) * N_ + n, isbf);
    } else {
        int r = idx - BN * 3;
        if (r < BM) {
            int b = r / M_, m = r % M_;
            float s = 0.f;
            for (int c = 0; c < 3; c++) {
                float v = rdval(xg, (b * 3 + c) * M_ + m, isbf);
                gt[r * 3 + c] = v;
                gT3[(b * 3 + c) * M_ + m] = v;
                s = fmaf(v, v, s);
            }
            gn[r] = s;
        }
    }
}

// ---------------------------------------------------------------- nearest D=3 body
DEV void nearest3_body(int blk, const float* __restrict__ q, const float* __restrict__ gt,
                       const float* __restrict__ gn, int* __restrict__ nearest) {
    int sub = threadIdx.x & 15;
    int pt = blk * 16 + (threadIdx.x >> 4);
    int b = pt >> 12;
    float q0 = q[pt * 3], q1 = q[pt * 3 + 1], q2 = q[pt * 3 + 2];
    float qn = q0 * q0 + q1 * q1 + q2 * q2;
    const float* gb = gt + (size_t)b * M_ * 3;
    const float* gnb = gn + b * M_;
    float best = 1e30f; int bi = 0x7fffffff;
    for (int j = 0; j < 32; j++) {
        int m = sub + 16 * j;
        float dot = q0 * gb[m * 3] + q1 * gb[m * 3 + 1] + q2 * gb[m * 3 + 2];
        float dv = qn + gnb[m] - 2.f * dot;
        if (dv < best || (dv == best && m < bi)) { best = dv; bi = m; }
    }
    for (int off = 8; off; off >>= 1) {
        float ov = __shfl_xor(best, off);
        int oi = __shfl_xor(bi, off);
        if (ov < best || (ov == best && oi < bi)) { best = ov; bi = oi; }
    }
    if (sub == 0) nearest[pt] = clampi(bi, M_);
}

// ---------------------------------------------------------------- nearest D=64 v4: q staged in LDS, 8-row chunks
DEV void nearest64_body_v4(int blk, const float* __restrict__ q,
                           const float* __restrict__ gT, const float* __restrict__ gn,
                           int* __restrict__ nearest,
                           float (*__restrict__ lg)[512], float (*__restrict__ ql)[64]) {
    int lane = threadIdx.x & 63;
    int tid = threadIdx.x;
    int w = __builtin_amdgcn_readfirstlane(threadIdx.x >> 6);
    int pt0 = blk * 16 + w * 4;
    int b = pt0 >> 12;
    const float* gTb = gT + (size_t)b * 64 * M_;
    {
        const float4* q4 = (const float4*)(q + (size_t)(blk * 16) * 64);
        ((float4*)ql)[tid] = q4[tid];
    }
    float qn[4] = {0.f, 0.f, 0.f, 0.f};
    float d[4][8] = {};
#pragma clang loop unroll(disable)
    for (int ch = 0; ch < 8; ch++) {
        __syncthreads();
        {
            const float4* src = (const float4*)(gTb + (size_t)ch * 8 * M_);
            float4* dst = (float4*)lg;
#pragma unroll
            for (int i = 0; i < 4; i++) {
                int idx = i * 256 + tid;
                dst[idx] = src[idx];
            }
        }
        __syncthreads();
#pragma unroll
        for (int j = 0; j < 8; j++) {
            float4 g0 = *(const float4*)&lg[j][4 * lane];
            float4 g1 = *(const float4*)&lg[j][256 + 4 * lane];
#pragma unroll
            for (int p = 0; p < 4; p++) {
                float qc = ql[w * 4 + p][ch * 8 + j];
                qn[p] = fmaf(qc, qc, qn[p]);
                d[p][0] = fmaf(qc, g0.x, d[p][0]); d[p][1] = fmaf(qc, g0.y, d[p][1]);
                d[p][2] = fmaf(qc, g0.z, d[p][2]); d[p][3] = fmaf(qc, g0.w, d[p][3]);
                d[p][4] = fmaf(qc, g1.x, d[p][4]); d[p][5] = fmaf(qc, g1.y, d[p][5]);
                d[p][6] = fmaf(qc, g1.z, d[p][6]); d[p][7] = fmaf(qc, g1.w, d[p][7]);
            }
        }
    }
    const float* gnb = gn + b * M_;
    float4 n0 = *(const float4*)(gnb + 4 * lane);
    float4 n1 = *(const float4*)(gnb + 256 + 4 * lane);
    float nn[8] = {n0.x, n0.y, n0.z, n0.w, n1.x, n1.y, n1.z, n1.w};
#pragma clang loop unroll(disable)
    for (int p = 0; p < 4; p++) {
        float best = 1e30f; int bi = 0;
#pragma unroll
        for (int i = 0; i < 8; i++) {
            int m = (i < 4) ? (4 * lane + i) : (256 + 4 * lane + i - 4);
            float dv = qn[p] + nn[i] - 2.f * d[p][i];
            if (dv < best || (dv == best && m < bi)) { best = dv; bi = m; }
        }
        for (int off = 32; off; off >>= 1) {
            float ov = __shfl_xor(best, off);
            int oi = __shfl_xor(bi, off);
            if (ov < best || (ov == best && oi < bi)) { best = ov; bi = oi; }
        }
        if (lane == 0) nearest[pt0 + p] = clampi(bi, M_);
    }
}

// ---------------------------------------------------------------- exact top-50 via radix-select
DEV void select50(const float dd[8], const int mreg[8], int lane,
                  int* __restrict__ rowp, int* __restrict__ idxrow) {
    u64 key[8];
#pragma unroll
    for (int i = 0; i < 8; i++) {
        unsigned u = __float_as_uint(dd[i]);
        if (u == 0x80000000u) u = 0u;                     // -0.0 -> +0.0
        u = (u & 0x80000000u) ? ~u : (u | 0x80000000u);   // order-preserving map
        key[i] = ((u64)u << 9) | (u64)(unsigned)mreg[i];
    }
    u64 kmin = key[0];
#pragma unroll
    for (int i = 1; i < 8; i++) kmin = key[i] < kmin ? key[i] : kmin;
    for (int off = 32; off; off >>= 1) {
        u64 o = __shfl_xor(kmin, off);
        kmin = o < kmin ? o : kmin;
    }
    u64 res = 0;
#pragma clang loop unroll(disable)
    for (int bit = 40; bit >= 0; --bit) {
        u64 t = res | ((u64)1 << bit);
        int c = 0;
#pragma unroll
        for (int i = 0; i < 8; i++) c += (key[i] < t) ? 1 : 0;
        u64 b0 = __ballot(c & 1), b1 = __ballot(c & 2), b2 = __ballot(c & 4), b3 = __ballot(c & 8);
        int tot = __popcll(b0) + 2 * __popcll(b1) + 4 * __popcll(b2) + 8 * __popcll(b3);
        if (tot <= K_ - 1) res = t;
    }
    int lc = 0, loc[8];
    bool sel[8];
#pragma unroll
    for (int i = 0; i < 8; i++) {
        sel[i] = (key[i] <= res) && (key[i] != kmin);
        loc[i] = lc;
        lc += sel[i] ? 1 : 0;
    }
    u64 lmask = ((u64)1 << lane) - 1;
    u64 c0 = __ballot(lc & 1), c1 = __ballot(lc & 2), c2 = __ballot(lc & 4), c3 = __ballot(lc & 8);
    int pre = __popcll(c0 & lmask) + 2 * __popcll(c1 & lmask)
            + 4 * __popcll(c2 & lmask) + 8 * __popcll(c3 & lmask);
#pragma unroll
    for (int i = 0; i < 8; i++) {
        if (key[i] == kmin) { rowp[0] = mreg[i]; idxrow[0] = mreg[i]; }
        if (sel[i]) { int p = 1 + pre + loc[i]; rowp[p] = mreg[i]; idxrow[p] = mreg[i]; }
    }
}

// ---------------------------------------------------------------- grid KNN D=3 (unstaged distance) + radix select
DEV void nbr3_body(int blk, const float* __restrict__ g, const float* __restrict__ gT,
                   const float* __restrict__ gn, const float* __restrict__ Pg,
                   int* __restrict__ nbr, float* __restrict__ T1, float* __restrict__ T2,
                   float* __restrict__ Mn, float* __restrict__ Mx,
                   int (*__restrict__ idxb)[64]) {
    int lane = threadIdx.x & 63, w = threadIdx.x >> 6;
    int row = blk * 4 + w;
    int b = row >> 9;
    const float* grow = g + (size_t)row * 3;
    float qn = gn[row];
    const float* gTb = gT + (size_t)b * 3 * M_;
    const float* gnb = gn + b * M_;
    float d[8] = {0.f, 0.f, 0.f, 0.f, 0.f, 0.f, 0.f, 0.f};
    {
        float qs[3];
#pragma unroll
        for (int c = 0; c < 3; c++) qs[c] = grow[c];
#pragma unroll
        for (int c = 0; c < 3; c++) {
            float qc = qs[c];
            float4 g0 = *(const float4*)(gTb + c * M_ + 4 * lane);
            float4 g1 = *(const float4*)(gTb + c * M_ + 256 + 4 * lane);
            d[0] = fmaf(qc, g0.x, d[0]); d[1] = fmaf(qc, g0.y, d[1]);
            d[2] = fmaf(qc, g0.z, d[2]); d[3] = fmaf(qc, g0.w, d[3]);
            d[4] = fmaf(qc, g1.x, d[4]); d[5] = fmaf(qc, g1.y, d[5]);
            d[6] = fmaf(qc, g1.z, d[6]); d[7] = fmaf(qc, g1.w, d[7]);
        }
    }
    float4 n0 = *(const float4*)(gnb + 4 * lane);
    float4 n1 = *(const float4*)(gnb + 256 + 4 * lane);
    float dd[8];
    dd[0] = qn + n0.x - 2.f * d[0]; dd[1] = qn + n0.y - 2.f * d[1];
    dd[2] = qn + n0.z - 2.f * d[2]; dd[3] = qn + n0.w - 2.f * d[3];
    dd[4] = qn + n1.x - 2.f * d[4]; dd[5] = qn + n1.y - 2.f * d[5];
    dd[6] = qn + n1.z - 2.f * d[6]; dd[7] = qn + n1.w - 2.f * d[7];
    int mreg[8];
#pragma unroll
    for (int i = 0; i < 8; i++) mreg[i] = (i < 4) ? (4 * lane + i) : (256 + 4 * lane + i - 4);
    select50(dd, mreg, lane, nbr + (size_t)row * K_, idxb[w]);
    int myIdx = idxb[w][lane];
    const float* Pgb = Pg + (size_t)b * M_ * 64;
    float t1 = 0.f, t2 = 0.f, mn = 1e30f, mx = -1e30f;
#pragma unroll 7
    for (int k = 1; k < K_; k++) {
        int idx = clampi(__shfl(myIdx, k), M_);
        float v = Pgb[(size_t)idx * 64 + lane];
        t1 += v; t2 = fmaf(v, v, t2);
        mn = fminf(mn, v); mx = fmaxf(mx, v);
    }
    size_t o = (size_t)row * 64 + lane;
    T1[o] = t1; T2[o] = t2; Mn[o] = mn; Mx[o] = mx;
}

// ---------------------------------------------------------------- grid KNN D=64 (staged distance) + radix select
DEV void nbr64_body(int blk, const float* __restrict__ g, const float* __restrict__ gT,
                    const float* __restrict__ gn, const float* __restrict__ Pg,
                    int* __restrict__ nbr, float* __restrict__ T1, float* __restrict__ T2,
                    float* __restrict__ Mn, float* __restrict__ Mx,
                    float (*__restrict__ lg)[512], float (*__restrict__ ql)[64],
                    int (*__restrict__ idxb)[64]) {
    int lane = threadIdx.x & 63, w = threadIdx.x >> 6;
    int tid = threadIdx.x;
    int row = blk * 4 + w;
    int b = row >> 9;
    float qn = gn[row];
    const float* gTb = gT + (size_t)b * 64 * M_;
    const float* gnb = gn + b * M_;
    if (tid < 64) {
        const float4* q4 = (const float4*)(g + (size_t)(blk * 4) * 64);
        ((float4*)ql)[tid] = q4[tid];
    }
    float d[8] = {0.f, 0.f, 0.f, 0.f, 0.f, 0.f, 0.f, 0.f};
#pragma clang loop unroll(disable)
    for (int ch = 0; ch < 8; ch++) {
        __syncthreads();
        {
            const float4* src = (const float4*)(gTb + (size_t)ch * 8 * M_);
            float4* dst = (float4*)lg;
#pragma unroll
            for (int i = 0; i < 4; i++) {
                int idx = i * 256 + tid;
                dst[idx] = src[idx];
            }
        }
        __syncthreads();
#pragma unroll
        for (int j = 0; j < 8; j++) {
            float qc = ql[w][ch * 8 + j];   // uniform ds_read (broadcast)
            float4 g0 = *(const float4*)&lg[j][4 * lane];
            float4 g1 = *(const float4*)&lg[j][256 + 4 * lane];
            d[0] = fmaf(qc, g0.x, d[0]); d[1] = fmaf(qc, g0.y, d[1]);
            d[2] = fmaf(qc, g0.z, d[2]); d[3] = fmaf(qc, g0.w, d[3]);
            d[4] = fmaf(qc, g1.x, d[4]); d[5] = fmaf(qc, g1.y, d[5]);
            d[6] = fmaf(qc, g1.z, d[6]); d[7] = fmaf(qc, g1.w, d[7]);
        }
    }
    float4 n0 = *(const float4*)(gnb + 4 * lane);
    float4 n1 = *(const float4*)(gnb + 256 + 4 * lane);
    float dd[8];
    dd[0] = qn + n0.x - 2.f * d[0]; dd[1] = qn + n0.y - 2.f * d[1];
    dd[2] = qn + n0.z - 2.f * d[2]; dd[3] = qn + n0.w - 2.f * d[3];
    dd[4] = qn + n1.x - 2.f * d[4]; dd[5] = qn + n1.y - 2.f * d[5];
    dd[6] = qn + n1.z - 2.f * d[6]; dd[7] = qn + n1.w - 2.f * d[7];
    int mreg[8];
#pragma unroll
    for (int i = 0; i < 8; i++) mreg[i] = (i < 4) ? (4 * lane + i) : (256 + 4 * lane + i - 4);
    select50(dd, mreg, lane, nbr + (size_t)row * K_, idxb[w]);
    int myIdx = idxb[w][lane];
    const float* Pgb = Pg + (size_t)b * M_ * 64;
    float t1 = 0.f, t2 = 0.f, mn = 1e30f, mx = -1e30f;
#pragma unroll 7
    for (int k = 1; k < K_; k++) {
        int idx = clampi(__shfl(myIdx, k), M_);
        float v = Pgb[(size_t)idx * 64 + lane];
        t1 += v; t2 = fmaf(v, v, t2);
        mn = fminf(mn, v); mx = fmaxf(mx, v);
    }
    size_t o = (size_t)row * 64 + lane;
    T1[o] = t1; T2[o] = t2; Mn[o] = mn; Mx[o] = mx;
}

// ---------------------------------------------------------------- fused KNN launches
__global__ __launch_bounds__(256) void k_knn3(
    const float* __restrict__ q, const float* __restrict__ gt, const float* __restrict__ gT3,
    const float* __restrict__ gn, const float* __restrict__ Pg,
    int* __restrict__ nearest, int* __restrict__ nbr, float* __restrict__ T1,
    float* __restrict__ T2, float* __restrict__ Mn, float* __restrict__ Mx) {
    __shared__ int idxb[4][64];
    if (blockIdx.x < BN / 16) nearest3_body(blockIdx.x, q, gt, gn, nearest);
    else nbr3_body(blockIdx.x - BN / 16, gt, gT3, gn, Pg, nbr, T1, T2, Mn, Mx, idxb);
}
__global__ __launch_bounds__(256) void k_knn64(
    const float* __restrict__ q, const float* __restrict__ xgt, const float* __restrict__ gT,
    const float* __restrict__ gn, const float* __restrict__ Pg,
    int* __restrict__ nearest, int* __restrict__ nbr, float* __restrict__ T1,
    float* __restrict__ T2, float* __restrict__ Mn, float* __restrict__ Mx) {
    __shared__ float lg[8][512];   // 16 KB staging panel
    __shared__ float ql[16][64];   // 4 KB q rows
    __shared__ int idxb[4][64];    // 1 KB selected-index rows
    if (blockIdx.x < BN / 16) nearest64_body_v4(blockIdx.x, q, gT, gn, nearest, lg, ql);
    else nbr64_body(blockIdx.x - BN / 16, xgt, gT, gn, Pg, nbr, T1, T2, Mn, Mx, lg, ql, idxb);
}

// ---------------------------------------------------------------- deterministic block stats store
#define STATS_STORE_64(s1v, s2v, partial)                                         \
    {                                                                             \
        __shared__ float r1_[256], r2_[256];                                      \
        r1_[threadIdx.x] = (s1v); r2_[threadIdx.x] = (s2v);                       \
        __syncthreads();                                                          \
        if (threadIdx.x < 64) {                                                   \
            int t_ = threadIdx.x;                                                 \
            float a1_ = r1_[t_] + r1_[t_ + 64] + r1_[t_ + 128] + r1_[t_ + 192];   \
            float a2_ = r2_[t_] + r2_[t_ + 64] + r2_[t_ + 128] + r2_[t_ + 192];   \
            float* sp_ = (partial) + (size_t)blockIdx.x * 128;                    \
            sp_[t_] = a1_; sp_[64 + t_] = a2_;                                    \
        }                                                                         \
    }

// ---------------------------------------------------------------- Pg for stage A (D=3)
__global__ __launch_bounds__(256) void k_pgrid3(const float* __restrict__ g,
                                                const float* __restrict__ W1,
                                                float* __restrict__ Pg) {
    int lane = threadIdx.x & 63;
    int row = blockIdx.x * 4 + __builtin_amdgcn_readfirstlane(threadIdx.x >> 6);
    float c0 = g[row * 3], c1 = g[row * 3 + 1], c2 = g[row * 3 + 2];
    const float* wr = W1 + lane * 6;
    Pg[(size_t)row * 64 + lane] = fmaf(wr[0], c0, fmaf(wr[1], c1, wr[2] * c2));
}

// ---------------------------------------------------------------- fused grid prep (stages B/C)
__global__ __launch_bounds__(256) void k_gridprep(
    const float* __restrict__ xsrc, const int* __restrict__ FPS,
    const float* __restrict__ Wt, float* __restrict__ xgt, float* __restrict__ gT,
    float* __restrict__ gn, float* __restrict__ Pg) {
    int lane = threadIdx.x & 63, w = threadIdx.x >> 6;
    int row = blockIdx.x * 4 + w;
    int b = row >> 9, m = row & 511;
    int src = b * N_ + clampi(FPS[row], N_);
    float ge = xsrc[(size_t)src * 64 + lane];
    xgt[(size_t)row * 64 + lane] = ge;
    gT[((size_t)b * 64 + lane) * M_ + m] = ge;
    float s = 0.f, acc = 0.f;
#pragma unroll
    for (int c = 0; c < 64; c++) {
        float vc = __shfl(ge, c);
        s = fmaf(vc, vc, s);
        acc = fmaf(Wt[c * 64 + lane], vc, acc);
    }
    Pg[(size_t)row * 64 + lane] = acc;
    if (lane == 0) gn[row] = s;
}

// ---------------------------------------------------------------- fused prep + BN stats of y1
template <int D>
__global__ __launch_bounds__(256) void k_prep_stats(
    const float* __restrict__ q, const float* __restrict__ W1,
    const int* __restrict__ nearest, const float* __restrict__ T1,
    const float* __restrict__ T2, float* __restrict__ D0, float* __restrict__ S0,
    float* __restrict__ partial) {
    int lane = threadIdx.x & 63;
    int pt = blockIdx.x * 4 + __builtin_amdgcn_readfirstlane(threadIdx.x >> 6);
    int b = pt >> 12;
    float pa, pb;
    if constexpr (D == 3) {
        float c0 = q[pt * 3], c1 = q[pt * 3 + 1], c2 = q[pt * 3 + 2];
        const float* wr = W1 + lane * 6;
        pa = fmaf(wr[0], c0, fmaf(wr[1], c1, wr[2] * c2));
        pb = fmaf(wr[3], c0, fmaf(wr[4], c1, wr[5] * c2));
    } else {
        float ge = q[(size_t)pt * 64 + lane];
        pa = 0.f; pb = 0.f;
#pragma unroll
        for (int c = 0; c < 64; c++) {
            float sh = __shfl(ge, c);
            pa = fmaf(W1[c * 64 + lane], sh, pa);
            pb = fmaf(W1[(64 + c) * 64 + lane], sh, pb);
        }
    }
    float d0 = pb - pa, s0 = pb;
    size_t t = (size_t)pt * 64 + lane;
    D0[t] = d0;
    S0[t] = s0;
    size_t nr = ((size_t)b * M_ + clampi(nearest[pt], M_)) * 64 + lane;
    float t1 = T1[nr], t2 = T2[nr];
    float s1 = s0 + fmaf(49.f, d0, t1);
    float s2 = fmaf(s0, s0, fmaf(49.f * d0, d0, fmaf(2.f * d0, t1, t2)));
    STATS_STORE_64(s1, s2, partial)
}

// ---------------------------------------------------------------- stage-C output: bn+lrelu(max) exact
__global__ void k_apply0(const float* __restrict__ D0, const float* __restrict__ S0,
                         const int* __restrict__ nearest, const float* __restrict__ Mn,
                         const float* __restrict__ Mx, const float* __restrict__ prm,
                         float* __restrict__ xout) {
    int t = blockIdx.x * 256 + threadIdx.x;
    int pt = t >> 6, o = t & 63;
    int b = pt >> 12;
    size_t nr = ((size_t)b * M_ + clampi(nearest[pt], M_)) * 64 + o;
    float d0 = D0[t], s0 = S0[t];
    float a = prm[o], sh = prm[64 + o];
    float v = a > 0.f ? fmaxf(s0, d0 + Mx[nr]) : fminf(s0, d0 + Mn[nr]);
    xout[t] = lrelu(fmaf(a, v, sh));
}

// ---------------------------------------------------------------- pass1 via MFMA, 1 point/block (128 thr, 16KB LDS)
// Identical per-point arithmetic to the 2-pt version (bit-identical y):
// Z-build order, MFMA sequence, reduction unchanged. Doubling blocks and
// halving LDS raises blocks/CU ~5->9 for latency hiding of the
// nearest->nbr->ub gather chain.
__global__ __launch_bounds__(128) void k_pass1_mfma(
    const float* __restrict__ ub, const float* __restrict__ D0,
    const float* __restrict__ S0, const int* __restrict__ nearest,
    const int* __restrict__ nbr, const float* __restrict__ prm1,
    const u16* __restrict__ wf, const float* __restrict__ zero64,
    float* __restrict__ partial,
    float* __restrict__ mn_out, float* __restrict__ mx_out) {
    __shared__ u16 Zs[2][4096];   // [hi/lo][64 rows * 64 cols], 16 KB
    float* ls1 = (float*)&Zs[0][0];   // aliased after MFMA reads (512 B)
    float* ls2 = ls1 + 64;
    int l = threadIdx.x & 63;
    int nh = threadIdx.x >> 6;       // wave = o-half
    int pt = blockIdx.x, b = pt >> 12;
    bf8v whi[2][2], wlo[2][2];
#pragma unroll
    for (int nt = 0; nt < 2; nt++)
#pragma unroll
        for (int s = 0; s < 2; s++) {
            int fi = (((nh * 2 + nt) * 2 + s) * 64 + l) * 8;
            whi[nt][s] = *(const bf8v*)(wf + fi);
            wlo[nt][s] = *(const bf8v*)(wf + 4096 + fi);
        }
    // ---- Z build: 128 threads, thread = (k row, c-half) ----
    {
        int k = threadIdx.x & 63, ch = threadIdx.x >> 6;
        int nr = clampi(nearest[pt], M_);
        const int* nrow = nbr + ((size_t)b * M_ + nr) * K_;
        int idx = (k >= 1 && k < K_) ? clampi(nrow[k], M_) : 0;
        const float4* src = ((k == 0) ? (const float4*)(S0 + (size_t)pt * 64)
                                      : (const float4*)(ub + ((size_t)b * M_ + idx) * 64)) + ch * 8;
        const float4* d4 = ((k == 0) ? (const float4*)zero64
                                     : (const float4*)(D0 + (size_t)pt * 64)) + ch * 8;
        const float4* a4 = (const float4*)(prm1) + ch * 8;
        const float4* s4 = (const float4*)(prm1 + 64) + ch * 8;
        bool pad = (k >= K_);        // zero rows 50..63 (masked out of min/max later)
        char* zh = (char*)&Zs[0][0];
        char* zl = (char*)&Zs[1][0];
        int swz = (k & 7) << 4;
#pragma unroll
        for (int q2 = 0; q2 < 4; q2++) {
            unsigned hv[4], lv[4];
#pragma unroll
            for (int h = 0; h < 2; h++) {
                float4 u = src[q2 * 2 + h], d = d4[q2 * 2 + h];
                float4 a = a4[q2 * 2 + h];
                if (k == 0) {   // fold bn into u for the center row (bit-exact old path)
                    float4 s = s4[q2 * 2 + h];
                    u.x = fmaf(a.x, u.x, s.x); u.y = fmaf(a.y, u.y, s.y);
                    u.z = fmaf(a.z, u.z, s.z); u.w = fmaf(a.w, u.w, s.w);
                }
                float z0 = lrelu(fmaf(a.x, d.x, u.x));
                float z1 = lrelu(fmaf(a.y, d.y, u.y));
                float z2 = lrelu(fmaf(a.z, d.z, u.z));
                float z3 = lrelu(fmaf(a.w, d.w, u.w));
                if (pad) { z0 = 0.f; z1 = 0.f; z2 = 0.f; z3 = 0.f; }
                unsigned h01 = cvtpk(z0, z1), h23 = cvtpk(z2, z3);
                float r0 = z0 - __uint_as_float(h01 << 16);
                float r1 = z1 - __uint_as_float(h01 & 0xFFFF0000u);
                float r2 = z2 - __uint_as_float(h23 << 16);
                float r3 = z3 - __uint_as_float(h23 & 0xFFFF0000u);
                hv[h * 2] = h01; hv[h * 2 + 1] = h23;
                lv[h * 2] = cvtpk(r0, r1); lv[h * 2 + 1] = cvtpk(r2, r3);
            }
            int ad = k * 128 + ((ch * 64 + q2 * 16) ^ swz);
            *(uint4*)(zh + ad) = make_uint4(hv[0], hv[1], hv[2], hv[3]);
            *(uint4*)(zl + ad) = make_uint4(lv[0], lv[1], lv[2], lv[3]);
        }
    }
    __syncthreads();
    // ---- MFMA: wave nh computes Y[64k x 32o] ----
    const char* zh = (const char*)&Zs[0][0];
    const char* zl = (const char*)&Zs[1][0];
    f4v acc[4][2] = {};
#pragma unroll
    for (int s = 0; s < 2; s++) {
        bf8v ah[4], al[4];
#pragma unroll
        for (int m = 0; m < 4; m++) {
            int row = m * 16 + (l & 15);
            int ad = row * 128 + (((s * 64) + ((l >> 4) * 16)) ^ ((row & 7) << 4));
            ah[m] = *(const bf8v*)(zh + ad);
            al[m] = *(const bf8v*)(zl + ad);
        }
#pragma unroll
        for (int m = 0; m < 4; m++)
#pragma unroll
            for (int nt = 0; nt < 2; nt++) {
                acc[m][nt] = __builtin_amdgcn_mfma_f32_16x16x32_bf16(ah[m], whi[nt][s], acc[m][nt], 0, 0, 0);
                acc[m][nt] = __builtin_amdgcn_mfma_f32_16x16x32_bf16(al[m], whi[nt][s], acc[m][nt], 0, 0, 0);
                acc[m][nt] = __builtin_amdgcn_mfma_f32_16x16x32_bf16(ah[m], wlo[nt][s], acc[m][nt], 0, 0, 0);
            }
    }
    __syncthreads();   // Zs reads complete; ls1/ls2 alias region now safe to write
    int rg = (l >> 4) * 4;
#pragma unroll
    for (int nt = 0; nt < 2; nt++) {
        float s1 = 0.f, s2 = 0.f, mn = 1e30f, mx = -1e30f;
#pragma unroll
        for (int m = 0; m < 4; m++)
#pragma unroll
            for (int i = 0; i < 4; i++) {
                int kk = m * 16 + rg + i;
                float v = acc[m][nt][i];
                if (kk < K_) { s1 += v; s2 = fmaf(v, v, s2); mn = fminf(mn, v); mx = fmaxf(mx, v); }
            }
        for (int off = 16; off <= 32; off <<= 1) {
            s1 += __shfl_xor(s1, off); s2 += __shfl_xor(s2, off);
            mn = fminf(mn, __shfl_xor(mn, off)); mx = fmaxf(mx, __shfl_xor(mx, off));
        }
        if (l < 16) {
            int o = nh * 32 + nt * 16 + l;
            mn_out[(size_t)pt * 64 + o] = mn;
            mx_out[(size_t)pt * 64 + o] = mx;
            ls1[o] = s1;
            ls2[o] = s2;
        }
    }
    __syncthreads();
    if (threadIdx.x < 64) {
        int t = threadIdx.x;
        float* sp = partial + (size_t)blockIdx.x * 128;
        sp[t] = ls1[t];
        sp[64 + t] = ls2[t];
    }
}

// ---------------------------------------------------------------- apply bn+lrelu to min/max (exact)
__global__ void k_apply(const float* __restrict__ mn, const float* __restrict__ mx,
                        const float* __restrict__ prm, float* __restrict__ xout) {
    int t = blockIdx.x * 256 + threadIdx.x;
    int o = t & 63;
    float a = prm[o], sh = prm[64 + o];
    float v = a > 0.f ? mx[t] : mn[t];
    xout[t] = lrelu(fmaf(a, v, sh));
}

// ---------------------------------------------------------------- fused reduce+finalize (32 blocks)
template <int NP, int O>
__global__ __launch_bounds__(256) void k_redfin(
    const float* __restrict__ partial, double* __restrict__ red,
    int* __restrict__ counter, int C,
    const float* __restrict__ g, const float* __restrict__ bt,
    float* __restrict__ prm) {
    constexpr int VALS = 2 * O;
    constexpr int G = NP / 32;
    int b = blockIdx.x;   // 32 blocks
    for (int v = threadIdx.x; v < VALS; v += 256) {
        const float* p = partial + (size_t)b * G * VALS + v;
        double s = 0.0;
        for (int k = 0; k < G; k++) s += p[(size_t)k * VALS];
        red[(size_t)b * VALS + v] = s;
    }
    __threadfence();
    __syncthreads();
    __shared__ bool isLast;
    if (threadIdx.x == 0) isLast = (atomicAdd(counter, 1) == 31);
    __syncthreads();
    if (!isLast) return;
    __threadfence();
    for (int o = threadIdx.x; o < O; o += 256) {
        double s1 = 0.0, s2 = 0.0;
#pragma unroll
        for (int k = 0; k < 32; k++) {
            s1 += red[(size_t)k * VALS + o];
            s2 += red[(size_t)k * VALS + O + o];
        }
        double m = s1 / C, var = s2 / C - m * m;
        if (var < 0) var = 0;
        float sc = g[o] / sqrtf((float)var + EPS_);
        prm[o] = sc;
        prm[O + o] = bt[o] - (float)m * sc;
    }
}

// ---------------------------------------------------------------- W6 conv (192->512), Wt-coalesced, 4-row tiles
__global__ __launch_bounds__(256) void k_conv_w6(
    const float* __restrict__ x1gt, const float* __restrict__ x2gt,
    const float* __restrict__ x3t, const int* __restrict__ FPS,
    const float* __restrict__ W6t, float* __restrict__ y6, float* __restrict__ partial) {
    __shared__ float vl[4][192];
    int b = blockIdx.x / 128;
    int m0 = (blockIdx.x % 128) * 4;
    for (int i = threadIdx.x; i < 4 * 192; i += 256) {
        int mi = i / 192, c = i % 192;
        float v;
        if (c < 128) {
            const float* src = c < 64 ? x1gt : x2gt;
            v = src[((size_t)b * M_ + m0 + mi) * 64 + (c & 63)];
        } else {
            int s = b * N_ + clampi(FPS[b * M_ + m0 + mi], N_);
            v = x3t[(size_t)s * 64 + (c - 128)];
        }
        vl[mi][c] = v;
    }
    __syncthreads();
    float acc0[4] = {0}, acc1[4] = {0};
    int o0 = threadIdx.x, o1 = threadIdx.x + 256;
    for (int c = 0; c < 192; c++) {
        float w0 = W6t[c * 512 + o0];
        float w1 = W6t[c * 512 + o1];
#pragma unroll
        for (int m = 0; m < 4; m++) { float v = vl[m][c]; acc0[m] = fmaf(w0, v, acc0[m]); acc1[m] = fmaf(w1, v, acc1[m]); }
    }
    float s1a = 0, s2a = 0, s1b = 0, s2b = 0;
    for (int m = 0; m < 4; m++) {
        float ya = acc0[m], yb = acc1[m];
        y6[((size_t)b * M_ + m0 + m) * 512 + o0] = ya;
        y6[((size_t)b * M_ + m0 + m) * 512 + o1] = yb;
        s1a += ya; s2a = fmaf(ya, ya, s2a); s1b += yb; s2b = fmaf(yb, yb, s2b);
    }
    float* sp = partial + (size_t)blockIdx.x * 1024;
    sp[o0] = s1a; sp[512 + o0] = s2a;
    sp[o1] = s1b; sp[512 + o1] = s2b;
}

// ---------------------------------------------------------------- bn6+lrelu+max over M (128 blocks)
__global__ void k_maxM(const float* __restrict__ y6, const float* __restrict__ prm,
                       float* __restrict__ xgmax) {
    int blk = blockIdx.x;            // B_*64
    int b = blk >> 6;
    int obase = (blk & 63) << 3;
    int o = obase + (threadIdx.x & 7);
    int mg = threadIdx.x >> 3;       // 32 m-groups
    float a = prm[o], sh = prm[512 + o];
    float mx = -1e30f;
    for (int m = mg; m < M_; m += 32)
        mx = fmaxf(mx, lrelu(fmaf(a, y6[((size_t)b * M_ + m) * 512 + o], sh)));
    __shared__ float red[256];
    red[threadIdx.x] = mx;
    __syncthreads();
    for (int s = 128; s >= 8; s >>= 1) {
        if (threadIdx.x < s) red[threadIdx.x] = fmaxf(red[threadIdx.x], red[threadIdx.x + s]);
        __syncthreads();
    }
    if (threadIdx.x < 8) xgmax[b * 512 + obase + threadIdx.x] = red[threadIdx.x];
}

// ---------------------------------------------------------------- P7: wave per output (fixed xor tree)
__global__ __launch_bounds__(256) void k_p7(const float* __restrict__ xgmax,
                                            const float* __restrict__ W7,
                                            float* __restrict__ p7) {
    int lane = threadIdx.x & 63, w = threadIdx.x >> 6;
    int t = blockIdx.x * 4 + w;     // 0..255
    int b = t >> 7, o = t & 127;
    float acc = 0.f;
#pragma unroll
    for (int j = 0; j < 8; j++) {
        int c = j * 64 + lane;
        acc = fmaf(W7[o * 704 + c], xgmax[b * 512 + c], acc);
    }
    for (int off = 32; off; off >>= 1) acc += __shfl_xor(acc, off);
    if (lane == 0) p7[t] = acc;
}

// ---------------------------------------------------------------- W7 conv (192-col part) via MFMA, 16 items/block
__global__ __launch_bounds__(256) void k_conv_w7m(
    const float* __restrict__ x1t, const float* __restrict__ x2t,
    const float* __restrict__ x3t, const float* __restrict__ p7,
    const u16* __restrict__ wf7, float* __restrict__ y7, float* __restrict__ partial) {
    __shared__ u16 Zh[16][200], Zl[16][200];   // 12.5 KB
    int tid = threadIdx.x;
    int l = tid & 63, w = tid >> 6;
    int item0 = blockIdx.x * 16;
    int b = blockIdx.x >> 8;                    // 512 blocks, 256 per batch
    bf8v wh[2][6], wl[2][6];
#pragma unroll
    for (int nt = 0; nt < 2; nt++)
#pragma unroll
        for (int s = 0; s < 6; s++) {
            int fi = (((2 * w + nt) * 6 + s) * 64 + l) * 8;
            wh[nt][s] = *(const bf8v*)(wf7 + fi);
            wl[nt][s] = *(const bf8v*)(wf7 + 24576 + fi);
        }
    {
        int item = tid >> 4, seg = tid & 15;
        if (seg < 12) {
            const float* sp_;
            size_t base = (size_t)(item0 + item) * 64;
            if (seg < 4) sp_ = x1t + base + seg * 16;
            else if (seg < 8) sp_ = x2t + base + (seg - 4) * 16;
            else sp_ = x3t + base + (seg - 8) * 16;
            float f[16];
#pragma unroll
            for (int i = 0; i < 4; i++) {
                float4 v = ((const float4*)sp_)[i];
                f[4 * i] = v.x; f[4 * i + 1] = v.y; f[4 * i + 2] = v.z; f[4 * i + 3] = v.w;
            }
            unsigned hp[8], lp[8];
#pragma unroll
            for (int e = 0; e < 8; e++) {
                unsigned h = cvtpk(f[2 * e], f[2 * e + 1]);
                float r0 = f[2 * e] - __uint_as_float(h << 16);
                float r1 = f[2 * e + 1] - __uint_as_float(h & 0xFFFF0000u);
                hp[e] = h;
                lp[e] = cvtpk(r0, r1);
            }
            uint4* dh = (uint4*)&Zh[item][seg * 16];
            uint4* dl = (uint4*)&Zl[item][seg * 16];
            dh[0] = make_uint4(hp[0], hp[1], hp[2], hp[3]);
            dh[1] = make_uint4(hp[4], hp[5], hp[6], hp[7]);
            dl[0] = make_uint4(lp[0], lp[1], lp[2], lp[3]);
            dl[1] = make_uint4(lp[4], lp[5], lp[6], lp[7]);
        }
    }
    __syncthreads();
    f4v acc[2] = {};
#pragma unroll
    for (int s = 0; s < 6; s++) {
        int row = l & 15, col = s * 32 + (l >> 4) * 8;
        bf8v ah = *(const bf8v*)&Zh[row][col];
        bf8v al = *(const bf8v*)&Zl[row][col];
#pragma unroll
        for (int nt = 0; nt < 2; nt++) {
            acc[nt] = __builtin_amdgcn_mfma_f32_16x16x32_bf16(ah, wh[nt][s], acc[nt], 0, 0, 0);
            acc[nt] = __builtin_amdgcn_mfma_f32_16x16x32_bf16(al, wh[nt][s], acc[nt], 0, 0, 0);
            acc[nt] = __builtin_amdgcn_mfma_f32_16x16x32_bf16(ah, wl[nt][s], acc[nt], 0, 0, 0);
        }
    }
#pragma unroll
    for (int nt = 0; nt < 2; nt++) {
        int o = (2 * w + nt) * 16 + (l & 15);
        float pv = p7[b * 128 + o];
        float s1 = 0.f, s2 = 0.f;
#pragma unroll
        for (int i = 0; i < 4; i++) {
            int item = (l >> 4) * 4 + i;
            float yv = pv + acc[nt][i];
            y7[(size_t)(item0 + item) * 128 + o] = yv;
            s1 += yv; s2 = fmaf(yv, yv, s2);
        }
        for (int off = 16; off <= 32; off <<= 1) {
            s1 += __shfl_xor(s1, off);
            s2 += __shfl_xor(s2, off);
        }
        if (l < 16) {
            float* sp = partial + (size_t)blockIdx.x * 256;
            sp[o] = s1;
            sp[128 + o] = s2;
        }
    }
}

// ---------------------------------------------------------------- W8 conv (128->64), Wt-coalesced
__global__ __launch_bounds__(256) void k_conv_w8(
    const float* __restrict__ y7, const float* __restrict__ prm7,
    const float* __restrict__ W8t, float* __restrict__ y8, float* __restrict__ partial) {
    int lane = threadIdx.x & 63;
    int item = blockIdx.x * 4 + (threadIdx.x >> 6);
    float W0[64], W1r[64];
#pragma unroll
    for (int c = 0; c < 64; c++) {
        W0[c] = W8t[c * 64 + lane];
        W1r[c] = W8t[(64 + c) * 64 + lane];
    }
    float a0 = prm7[lane], sh0 = prm7[128 + lane];
    float a1 = prm7[64 + lane], sh1 = prm7[128 + 64 + lane];
    float z0 = lrelu(fmaf(a0, y7[(size_t)item * 128 + lane], sh0));
    float z1 = lrelu(fmaf(a1, y7[(size_t)item * 128 + 64 + lane], sh1));
    float acc = 0.f;
#pragma unroll
    for (int c = 0; c < 64; c++) {
        acc = fmaf(W0[c], __shfl(z0, c), acc);
        acc = fmaf(W1r[c], __shfl(z1, c), acc);
    }
    y8[(size_t)item * 64 + lane] = acc;
    STATS_STORE_64(acc, acc * acc, partial)
}

// ---------------------------------------------------------------- final: bn8+lrelu, W9t -> out
__global__ __launch_bounds__(256) void k_final(
    const float* __restrict__ y8, const float* __restrict__ prm8,
    const float* __restrict__ W9t, void* __restrict__ out, const int* __restrict__ flag) {
    __shared__ float zl[2][64];
    int item0 = blockIdx.x * 2;
    if (threadIdx.x < 128) {
        int it = threadIdx.x >> 6, c = threadIdx.x & 63;
        float z = fmaf(prm8[c], y8[(size_t)(item0 + it) * 64 + c], prm8[64 + c]);
        zl[it][c] = lrelu(z);
    }
    __syncthreads();
    int it = threadIdx.x >> 7, o = threadIdx.x & 127;
    float acc = 0.f;
#pragma unroll
    for (int c = 0; c < 64; c++) acc = fmaf(W9t[c * 128 + o], zl[it][c], acc);
    size_t oi = (size_t)(item0 + it) * 128 + o;
    if (*flag) ((bf16*)out)[oi] = __float2bfloat16(acc);
    else ((float*)out)[oi] = acc;
}

// ---------------------------------------------------------------- host
extern "C" void kernel_launch(void* const* d_in, const int* in_sizes, int n_in,
                              void* d_out, int out_size, void* d_ws, size_t ws_size,
                              hipStream_t stream) {
    (void)in_sizes; (void)n_in; (void)out_size; (void)ws_size;
    const void* x = d_in[0];
    const void* xgrid = d_in[1];
    const int* FPS = (const int*)d_in[2];

    char* ws = (char*)d_ws;
    size_t off = 0;
    auto alloc = [&](size_t bytes) -> char* {
        char* p = ws + off;
        off = (off + bytes + 255) & ~(size_t)255;
        return p;
    };
    int* flag       = (int*)alloc(256);
    int* counters   = (int*)alloc(256);
    float* zero64   = (float*)alloc(256);
    float* partials = (float*)alloc((size_t)8192 * 128 * sizeof(float));   // 4 MB (pass1 grid = 8192)
    double* redbuf  = (double*)alloc(32 * 1024 * sizeof(double));  // 256 KB
    float* prm      = (float*)alloc(8 * 1024 * sizeof(float));
    static const int wsz[9] = {384, 4096, 8192, 4096, 8192, 98304, 90112, 8192, 8192};
    static const int dims[8] = {64, 64, 64, 64, 64, 512, 128, 64};
    float* cW[9];
    for (int i = 0; i < 9; i++) cW[i] = (float*)alloc((size_t)wsz[i] * 4);
    float* cG[8];
    float* cB[8];
    for (int j = 0; j < 8; j++) {
        cG[j] = (float*)alloc((size_t)dims[j] * 4);
        cB[j] = (float*)alloc((size_t)dims[j] * 4);
    }
    float* W6t  = (float*)alloc((size_t)512 * 192 * 4);
    float* W7vt = (float*)alloc((size_t)128 * 192 * 4);
    float* W8t  = (float*)alloc((size_t)64 * 128 * 4);
    float* W9t  = (float*)alloc((size_t)128 * 64 * 4);
    float* W3t  = (float*)alloc((size_t)64 * 128 * 4);
    float* W5t  = (float*)alloc((size_t)64 * 128 * 4);
    u16* wf2    = (u16*)alloc((size_t)8192 * 2);    // W2 MFMA frags hi+lo
    u16* wf4    = (u16*)alloc((size_t)8192 * 2);    // W4 MFMA frags hi+lo
    u16* wf7    = (u16*)alloc((size_t)49152 * 2);   // W7 MFMA frags hi+lo
    float* xt    = (float*)alloc((size_t)BN * 3 * 4);
    float* gt    = (float*)alloc((size_t)BM * 3 * 4);
    float* gT3   = (float*)alloc((size_t)B_ * 3 * M_ * 4);
    float* gn    = (float*)alloc((size_t)BM * 4);
    int* nearest = (int*)alloc((size_t)BN * 4);
    int* nbr     = (int*)alloc((size_t)BM * K_ * 4);
    float* Pg    = (float*)alloc((size_t)BM * 64 * 4);
    float* ubuf  = (float*)alloc((size_t)BM * 64 * 4);
    float* x1t   = (float*)alloc((size_t)BN * 64 * 4);
    float* x2t   = (float*)alloc((size_t)BN * 64 * 4);
    float* x3t   = (float*)alloc((size_t)BN * 64 * 4);
    float* x1gt  = (float*)alloc((size_t)BM * 64 * 4);
    float* x2gt  = (float*)alloc((size_t)BM * 64 * 4);
    float* gT64  = (float*)alloc((size_t)B_ * 64 * M_ * 4);
    float* y6    = (float*)alloc((size_t)BM * 512 * 4);
    float* xgmax = (float*)alloc((size_t)B_ * 512 * 4);
    float* p7    = (float*)alloc((size_t)B_ * 128 * 4);
    float* y7    = (float*)alloc((size_t)BN * 128 * 4);
    float* y8    = (float*)alloc((size_t)BN * 64 * 4);
    // Aliases (lifetimes verified; same layout as passing rounds):
    float* D0b = y7;
    float* S0b = y7 + (size_t)BN * 64;
    float* mnb = y8;
    float* mxb = y6;
    float* T1b = y6;
    float* T2b = y6 + (size_t)BM * 64;
    float* Mnb = y6 + (size_t)2 * BM * 64;
    float* Mxb = y6 + (size_t)3 * BM * 64;

    hipMemsetAsync(counters, 0, 8 * sizeof(int), stream);
    hipMemsetAsync(zero64, 0, 256, stream);
    k_detect<<<1, 256, 0, stream>>>((const unsigned short*)x, flag);

    CvtArgs ca;
    for (int i = 0; i < 9; i++) ca.d[i] = {d_in[3 + i], cW[i], wsz[i]};
    for (int j = 0; j < 8; j++) {
        ca.d[9 + 2 * j]     = {d_in[12 + 2 * j], cG[j], dims[j]};
        ca.d[9 + 2 * j + 1] = {d_in[13 + 2 * j], cB[j], dims[j]};
    }
    k_convert<<<dim3(384, 25), 256, 0, stream>>>(ca, flag);
    CvtTArgs ct;
    ct.d[0] = {d_in[8],  W6t,  512, 192, 192, 0};    // W6
    ct.d[1] = {d_in[9],  W7vt, 128, 192, 704, 512};  // W7 variable cols
    ct.d[2] = {d_in[10], W8t,  64, 128, 128, 0};     // W8
    ct.d[3] = {d_in[11], W9t,  128, 64, 64, 0};      // W9
    ct.d[4] = {d_in[5],  W3t,  64, 128, 128, 0};     // W3 transposed (prep/gridprep)
    ct.d[5] = {d_in[7],  W5t,  64, 128, 128, 0};     // W5 transposed
    k_convT<<<dim3(384, 6), 256, 0, stream>>>(ct, flag);
    k_wfrag<<<dim3(16, 2), 256, 0, stream>>>(cW[1], cW[3], wf2, wf4);
    k_wfrag7<<<96, 256, 0, stream>>>(W7vt, wf7);
    k_transpose<<<(BN * 3 + BM + 255) / 256, 256, 0, stream>>>(x, xgrid, flag, xt, gt, gT3, gn);

    const int PG = BN / 4;         // wave-per-point grids (2048)
    const int EW = BN * 64 / 256;  // elementwise grids
    const int CK = BN * K_;
    const int KNNG = BN / 16 + BM / 4;   // 512 nearest blocks + 256 nbr blocks
    const int UBG = BM * 64 / 256;       // ubuf grid (256)

    // ---- stage A (D=3, W1,W2) ----
    k_pgrid3<<<BM / 4, 256, 0, stream>>>(gt, cW[0], Pg);
    k_knn3<<<KNNG, 256, 0, stream>>>(xt, gt, gT3, gn, Pg, nearest, nbr, T1b, T2b, Mnb, Mxb);
    k_prep_stats<3><<<PG, 256, 0, stream>>>(xt, cW[0], nearest, T1b, T2b, D0b, S0b, partials);
    k_redfin<2048, 64><<<32, 256, 0, stream>>>(partials, redbuf, counters + 0, CK, cG[0], cB[0], prm + 0 * 1024);
    k_ubuf<<<UBG, 256, 0, stream>>>(Pg, prm + 0 * 1024, ubuf);
    k_pass1_mfma<<<BN, 128, 0, stream>>>(ubuf, D0b, S0b, nearest, nbr, prm + 0 * 1024, wf2, zero64, partials, mnb, mxb);
    k_redfin<8192, 64><<<32, 256, 0, stream>>>(partials, redbuf, counters + 1, CK, cG[1], cB[1], prm + 1 * 1024);
    k_apply<<<EW, 256, 0, stream>>>(mnb, mxb, prm + 1 * 1024, x1t);

    // ---- stage B (D=64, W3,W4) ----
    k_gridprep<<<BM / 4, 256, 0, stream>>>(x1t, FPS, W3t, x1gt, gT64, gn, Pg);
    k_knn64<<<KNNG, 256, 0, stream>>>(x1t, x1gt, gT64, gn, Pg, nearest, nbr, T1b, T2b, Mnb, Mxb);
    k_prep_stats<64><<<PG, 256, 0, stream>>>(x1t, W3t, nearest, T1b, T2b, D0b, S0b, partials);
    k_redfin<2048, 64><<<32, 256, 0, stream>>>(partials, redbuf, counters + 2, CK, cG[2], cB[2], prm + 2 * 1024);
    k_ubuf<<<UBG, 256, 0, stream>>>(Pg, prm + 2 * 1024, ubuf);
    k_pass1_mfma<<<BN, 128, 0, stream>>>(ubuf, D0b, S0b, nearest, nbr, prm + 2 * 1024, wf4, zero64, partials, mnb, mxb);
    k_redfin<8192, 64><<<32, 256, 0, stream>>>(partials, redbuf, counters + 3, CK, cG[3], cB[3], prm + 3 * 1024);
    k_apply<<<EW, 256, 0, stream>>>(mnb, mxb, prm + 3 * 1024, x2t);

    // ---- stage C (D=64, W5 single conv) ----
    k_gridprep<<<BM / 4, 256, 0, stream>>>(x2t, FPS, W5t, x2gt, gT64, gn, Pg);
    k_knn64<<<KNNG, 256, 0, stream>>>(x2t, x2gt, gT64, gn, Pg, nearest, nbr, T1b, T2b, Mnb, Mxb);
    k_prep_stats<64><<<PG, 256, 0, stream>>>(x2t, W5t, nearest, T1b, T2b, D0b, S0b, partials);
    k_redfin<2048, 64><<<32, 256, 0, stream>>>(partials, redbuf, counters + 4, CK, cG[4], cB[4], prm + 4 * 1024);
    k_apply0<<<EW, 256, 0, stream>>>(D0b, S0b, nearest, Mnb, Mxb, prm + 4 * 1024, x3t);

    // ---- global MLP tail ----
    k_conv_w6<<<BM / 4, 256, 0, stream>>>(x1gt, x2gt, x3t, FPS, W6t, y6, partials);
    k_redfin<256, 512><<<32, 256, 0, stream>>>(partials, redbuf, counters + 5, BM, cG[5], cB[5], prm + 5 * 1024);
    k_maxM<<<B_ * 64, 256, 0, stream>>>(y6, prm + 5 * 1024, xgmax);
    k_p7<<<64, 256, 0, stream>>>(xgmax, cW[6], p7);
    k_conv_w7m<<<BN / 16, 256, 0, stream>>>(x1t, x2t, x3t, p7, wf7, y7, partials);
    k_redfin<512, 128><<<32, 256, 0, stream>>>(partials, redbuf, counters + 6, BN, cG[6], cB[6], prm + 6 * 1024);
    k_conv_w8<<<BN / 4, 256, 0, stream>>>(y7, prm + 6 * 1024, W8t, y8, partials);
    k_redfin<2048, 64><<<32, 256, 0, stream>>>(partials, redbuf, counters + 7, BN, cG[7], cB[7], prm + 7 * 1024);
    k_final<<<BN / 2, 256, 0, stream>>>(y8, prm + 7 * 1024, W9t, d_out, flag);
}

// Round 12
// 391.900 us; speedup vs baseline: 1.0931x; 1.0931x over previous
//
#include <hip/hip_runtime.h>
#include <hip/hip_bf16.h>

#define DEV __device__ __forceinline__
using bf16 = __hip_bfloat16;
using u16 = unsigned short;
using u64 = unsigned long long;

static constexpr int B_ = 2, N_ = 4096, M_ = 512, K_ = 50;
static constexpr int BN = B_ * N_;   // 8192 points
static constexpr int BM = B_ * M_;   // 1024 grid points
static constexpr float EPS_ = 1e-5f;

DEV float lrelu(float z) { return z < 0.f ? 0.2f * z : z; }
DEV int clampi(int v, int hi) { return ((unsigned)v < (unsigned)hi) ? v : 0; }

// bf16 split helpers (RNE, matches __float2bfloat16 for normals)
DEV u16 f2bfu(float f) {
    unsigned u = __float_as_uint(f);
    return (u16)((u + 0x7fffu + ((u >> 16) & 1u)) >> 16);
}
DEV float bfu2f(u16 h) { return __uint_as_float((unsigned)h << 16); }
// packed f32x2 -> bf16x2; hw round mode; 1-ulp diffs absorbed by lo plane.
DEV unsigned cvtpk(float a, float b) {
    unsigned r;
    asm("v_cvt_pk_bf16_f32 %0, %1, %2" : "=v"(r) : "v"(a), "v"(b));
    return r;
}

typedef short bf8v __attribute__((ext_vector_type(8)));   // 8 bf16 (4 VGPRs)
typedef float f4v __attribute__((ext_vector_type(4)));    // MFMA C/D

// ---------------------------------------------------------------- dtype detect
__global__ void k_detect(const unsigned short* __restrict__ xw, int* __restrict__ flag) {
    int t = threadIdx.x;
    int cnt = 0;
    for (int i = t; i < 4096; i += 256) {
        int e = (xw[i] >> 7) & 0xFF;
        if (e >= 100 && e <= 140) cnt++;
    }
    __shared__ int sh[256];
    sh[t] = cnt;
    __syncthreads();
    for (int s = 128; s; s >>= 1) { if (t < s) sh[t] += sh[t + s]; __syncthreads(); }
    if (t == 0) *flag = (sh[0] >= 3300) ? 1 : 0;
}

// ---------------------------------------------------------------- convert params to f32
struct CvtDesc { const void* src; float* dst; int n; };
struct CvtArgs { CvtDesc d[25]; };
__global__ void k_convert(CvtArgs a, const int* __restrict__ flag) {
    CvtDesc dd = a.d[blockIdx.y];
    int i = blockIdx.x * 256 + threadIdx.x;
    if (i >= dd.n) return;
    float v = (*flag) ? __bfloat162float(((const bf16*)dd.src)[i])
                      : ((const float*)dd.src)[i];
    dd.dst[i] = v;
}

// ---------------------------------------------------------------- transposed weight copies
struct CvtT { const void* src; float* dst; int O; int C; int stride; int off; };
struct CvtTArgs { CvtT d[6]; };
__global__ void k_convT(CvtTArgs a, const int* __restrict__ flag) {
    CvtT dd = a.d[blockIdx.y];
    int idx = blockIdx.x * 256 + threadIdx.x;
    if (idx >= dd.O * dd.C) return;
    int c = idx / dd.O, o = idx % dd.O;
    int si = o * dd.stride + dd.off + c;
    float v = (*flag) ? __bfloat162float(((const bf16*)dd.src)[si])
                      : ((const float*)dd.src)[si];
    dd.dst[idx] = v;   // dst[c*O + o]
}

// ---------------------------------------------------------------- W2/W4 bf16-split MFMA B-fragments
__global__ void k_wfrag(const float* __restrict__ Wa, const float* __restrict__ Wb,
                        u16* __restrict__ fa, u16* __restrict__ fb) {
    const float* W = blockIdx.y ? Wb : Wa;
    u16* f = blockIdx.y ? fb : fa;
    int t = blockIdx.x * 256 + threadIdx.x;   // 0..4095
    int j = t & 7, l = (t >> 3) & 63, s = (t >> 9) & 1, n = (t >> 10) & 3;
    int o = n * 16 + (l & 15);
    int c = s * 32 + (l >> 4) * 8 + j;
    float v = W[o * 64 + c];
    u16 hi = f2bfu(v);
    u16 lo = f2bfu(v - bfu2f(hi));
    f[t] = hi;
    f[4096 + t] = lo;
}

// ---------------------------------------------------------------- W7 (192-col part) bf16-split MFMA B-fragments
__global__ void k_wfrag7(const float* __restrict__ W7vt, u16* __restrict__ f) {
    int t = blockIdx.x * 256 + threadIdx.x;   // 0..24575
    int j = t & 7, l = (t >> 3) & 63;
    int rest = t >> 9;                        // 0..47
    int s = rest % 6, ot = rest / 6;
    int o = ot * 16 + (l & 15);
    int c = s * 32 + (l >> 4) * 8 + j;
    float v = W7vt[c * 128 + o];
    u16 hi = f2bfu(v);
    u16 lo = f2bfu(v - bfu2f(hi));
    f[t] = hi;
    f[24576 + t] = lo;
}

// ---------------------------------------------------------------- ubuf: a*Pg + s per stage (pass1 Z-build prefold)
__global__ void k_ubuf(const float* __restrict__ Pg, const float* __restrict__ prm,
                       float* __restrict__ ub) {
    int t = blockIdx.x * 256 + threadIdx.x;   // BM*64
    int c = t & 63;
    ub[t] = fmaf(prm[c], Pg[t], prm[64 + c]);
}

// ---------------------------------------------------------------- transpose (flat regrid; + gn for grid)
DEV float rdval(const void* p, int i, int isbf) {
    return isbf ? __bfloat162float(((const bf16*)p)[i]) : ((const float*)p)[i];
}
__global__ void k_transpose(const void* __restrict__ x, const void* __restrict__ xg,
                            const int* __restrict__ flag,
                            float* __restrict__ xt, float* __restrict__ gt,
                            float* __restrict__ gT3, float* __restrict__ gn) {
    int isbf = *flag;
    int idx = blockIdx.x * 256 + threadIdx.x;
    if (idx < BN * 3) {
        int c = idx / BN, i = idx % BN;
        int b = i / N_, n = i % N_;
        xt[i * 3 + c] = rdval(x, (b * 3 + c) * N_ + n, isbf);
    } else {
        int r = idx - BN * 3;
        if (r < BM) {
            int b = r / M_, m = r % M_;
            float s = 0.f;
            for (int c = 0; c < 3; c++) {
                float v = rdval(xg, (b * 3 + c) * M_ + m, isbf);
                gt[r * 3 + c] = v;
                gT3[(b * 3 + c) * M_ + m] = v;
                s = fmaf(v, v, s);
            }
            gn[r] = s;
        }
    }
}

// ---------------------------------------------------------------- nearest D=3 body
DEV void nearest3_body(int blk, const float* __restrict__ q, const float* __restrict__ gt,
                       const float* __restrict__ gn, int* __restrict__ nearest) {
    int sub = threadIdx.x & 15;
    int pt = blk * 16 + (threadIdx.x >> 4);
    int b = pt >> 12;
    float q0 = q[pt * 3], q1 = q[pt * 3 + 1], q2 = q[pt * 3 + 2];
    float qn = q0 * q0 + q1 * q1 + q2 * q2;
    const float* gb = gt + (size_t)b * M_ * 3;
    const float* gnb = gn + b * M_;
    float best = 1e30f; int bi = 0x7fffffff;
    for (int j = 0; j < 32; j++) {
        int m = sub + 16 * j;
        float dot = q0 * gb[m * 3] + q1 * gb[m * 3 + 1] + q2 * gb[m * 3 + 2];
        float dv = qn + gnb[m] - 2.f * dot;
        if (dv < best || (dv == best && m < bi)) { best = dv; bi = m; }
    }
    for (int off = 8; off; off >>= 1) {
        float ov = __shfl_xor(best, off);
        int oi = __shfl_xor(bi, off);
        if (ov < best || (ov == best && oi < bi)) { best = ov; bi = oi; }
    }
    if (sub == 0) nearest[pt] = clampi(bi, M_);
}

// ---------------------------------------------------------------- nearest D=64 v4: q staged in LDS, 8-row chunks
DEV void nearest64_body_v4(int blk, const float* __restrict__ q,
                           const float* __restrict__ gT, const float* __restrict__ gn,
                           int* __restrict__ nearest,
                           float (*__restrict__ lg)[512], float (*__restrict__ ql)[64]) {
    int lane = threadIdx.x & 63;
    int tid = threadIdx.x;
    int w = __builtin_amdgcn_readfirstlane(threadIdx.x >> 6);
    int pt0 = blk * 16 + w * 4;
    int b = pt0 >> 12;
    const float* gTb = gT + (size_t)b * 64 * M_;
    {
        const float4* q4 = (const float4*)(q + (size_t)(blk * 16) * 64);
        ((float4*)ql)[tid] = q4[tid];
    }
    float qn[4] = {0.f, 0.f, 0.f, 0.f};
    float d[4][8] = {};
#pragma clang loop unroll(disable)
    for (int ch = 0; ch < 8; ch++) {
        __syncthreads();
        {
            const float4* src = (const float4*)(gTb + (size_t)ch * 8 * M_);
            float4* dst = (float4*)lg;
#pragma unroll
            for (int i = 0; i < 4; i++) {
                int idx = i * 256 + tid;
                dst[idx] = src[idx];
            }
        }
        __syncthreads();
#pragma unroll
        for (int j = 0; j < 8; j++) {
            float4 g0 = *(const float4*)&lg[j][4 * lane];
            float4 g1 = *(const float4*)&lg[j][256 + 4 * lane];
#pragma unroll
            for (int p = 0; p < 4; p++) {
                float qc = ql[w * 4 + p][ch * 8 + j];
                qn[p] = fmaf(qc, qc, qn[p]);
                d[p][0] = fmaf(qc, g0.x, d[p][0]); d[p][1] = fmaf(qc, g0.y, d[p][1]);
                d[p][2] = fmaf(qc, g0.z, d[p][2]); d[p][3] = fmaf(qc, g0.w, d[p][3]);
                d[p][4] = fmaf(qc, g1.x, d[p][4]); d[p][5] = fmaf(qc, g1.y, d[p][5]);
                d[p][6] = fmaf(qc, g1.z, d[p][6]); d[p][7] = fmaf(qc, g1.w, d[p][7]);
            }
        }
    }
    const float* gnb = gn + b * M_;
    float4 n0 = *(const float4*)(gnb + 4 * lane);
    float4 n1 = *(const float4*)(gnb + 256 + 4 * lane);
    float nn[8] = {n0.x, n0.y, n0.z, n0.w, n1.x, n1.y, n1.z, n1.w};
#pragma clang loop unroll(disable)
    for (int p = 0; p < 4; p++) {
        float best = 1e30f; int bi = 0;
#pragma unroll
        for (int i = 0; i < 8; i++) {
            int m = (i < 4) ? (4 * lane + i) : (256 + 4 * lane + i - 4);
            float dv = qn[p] + nn[i] - 2.f * d[p][i];
            if (dv < best || (dv == best && m < bi)) { best = dv; bi = m; }
        }
        for (int off = 32; off; off >>= 1) {
            float ov = __shfl_xor(best, off);
            int oi = __shfl_xor(bi, off);
            if (ov < best || (ov == best && oi < bi)) { best = ov; bi = oi; }
        }
        if (lane == 0) nearest[pt0 + p] = clampi(bi, M_);
    }
}

// ---------------------------------------------------------------- exact top-50 via radix-select
DEV void select50(const float dd[8], const int mreg[8], int lane,
                  int* __restrict__ rowp, int* __restrict__ idxrow) {
    u64 key[8];
#pragma unroll
    for (int i = 0; i < 8; i++) {
        unsigned u = __float_as_uint(dd[i]);
        if (u == 0x80000000u) u = 0u;                     // -0.0 -> +0.0
        u = (u & 0x80000000u) ? ~u : (u | 0x80000000u);   // order-preserving map
        key[i] = ((u64)u << 9) | (u64)(unsigned)mreg[i];
    }
    u64 kmin = key[0];
#pragma unroll
    for (int i = 1; i < 8; i++) kmin = key[i] < kmin ? key[i] : kmin;
    for (int off = 32; off; off >>= 1) {
        u64 o = __shfl_xor(kmin, off);
        kmin = o < kmin ? o : kmin;
    }
    u64 res = 0;
#pragma clang loop unroll(disable)
    for (int bit = 40; bit >= 0; --bit) {
        u64 t = res | ((u64)1 << bit);
        int c = 0;
#pragma unroll
        for (int i = 0; i < 8; i++) c += (key[i] < t) ? 1 : 0;
        u64 b0 = __ballot(c & 1), b1 = __ballot(c & 2), b2 = __ballot(c & 4), b3 = __ballot(c & 8);
        int tot = __popcll(b0) + 2 * __popcll(b1) + 4 * __popcll(b2) + 8 * __popcll(b3);
        if (tot <= K_ - 1) res = t;
    }
    int lc = 0, loc[8];
    bool sel[8];
#pragma unroll
    for (int i = 0; i < 8; i++) {
        sel[i] = (key[i] <= res) && (key[i] != kmin);
        loc[i] = lc;
        lc += sel[i] ? 1 : 0;
    }
    u64 lmask = ((u64)1 << lane) - 1;
    u64 c0 = __ballot(lc & 1), c1 = __ballot(lc & 2), c2 = __ballot(lc & 4), c3 = __ballot(lc & 8);
    int pre = __popcll(c0 & lmask) + 2 * __popcll(c1 & lmask)
            + 4 * __popcll(c2 & lmask) + 8 * __popcll(c3 & lmask);
#pragma unroll
    for (int i = 0; i < 8; i++) {
        if (key[i] == kmin) { rowp[0] = mreg[i]; idxrow[0] = mreg[i]; }
        if (sel[i]) { int p = 1 + pre + loc[i]; rowp[p] = mreg[i]; idxrow[p] = mreg[i]; }
    }
}

// ---------------------------------------------------------------- grid KNN D=3 (unstaged distance) + radix select
DEV void nbr3_body(int blk, const float* __restrict__ g, const float* __restrict__ gT,
                   const float* __restrict__ gn, const float* __restrict__ Pg,
                   int* __restrict__ nbr, float* __restrict__ T1, float* __restrict__ T2,
                   float* __restrict__ Mn, float* __restrict__ Mx,
                   int (*__restrict__ idxb)[64]) {
    int lane = threadIdx.x & 63, w = threadIdx.x >> 6;
    int row = blk * 4 + w;
    int b = row >> 9;
    const float* grow = g + (size_t)row * 3;
    float qn = gn[row];
    const float* gTb = gT + (size_t)b * 3 * M_;
    const float* gnb = gn + b * M_;
    float d[8] = {0.f, 0.f, 0.f, 0.f, 0.f, 0.f, 0.f, 0.f};
    {
        float qs[3];
#pragma unroll
        for (int c = 0; c < 3; c++) qs[c] = grow[c];
#pragma unroll
        for (int c = 0; c < 3; c++) {
            float qc = qs[c];
            float4 g0 = *(const float4*)(gTb + c * M_ + 4 * lane);
            float4 g1 = *(const float4*)(gTb + c * M_ + 256 + 4 * lane);
            d[0] = fmaf(qc, g0.x, d[0]); d[1] = fmaf(qc, g0.y, d[1]);
            d[2] = fmaf(qc, g0.z, d[2]); d[3] = fmaf(qc, g0.w, d[3]);
            d[4] = fmaf(qc, g1.x, d[4]); d[5] = fmaf(qc, g1.y, d[5]);
            d[6] = fmaf(qc, g1.z, d[6]); d[7] = fmaf(qc, g1.w, d[7]);
        }
    }
    float4 n0 = *(const float4*)(gnb + 4 * lane);
    float4 n1 = *(const float4*)(gnb + 256 + 4 * lane);
    float dd[8];
    dd[0] = qn + n0.x - 2.f * d[0]; dd[1] = qn + n0.y - 2.f * d[1];
    dd[2] = qn + n0.z - 2.f * d[2]; dd[3] = qn + n0.w - 2.f * d[3];
    dd[4] = qn + n1.x - 2.f * d[4]; dd[5] = qn + n1.y - 2.f * d[5];
    dd[6] = qn + n1.z - 2.f * d[6]; dd[7] = qn + n1.w - 2.f * d[7];
    int mreg[8];
#pragma unroll
    for (int i = 0; i < 8; i++) mreg[i] = (i < 4) ? (4 * lane + i) : (256 + 4 * lane + i - 4);
    select50(dd, mreg, lane, nbr + (size_t)row * K_, idxb[w]);
    int myIdx = idxb[w][lane];
    const float* Pgb = Pg + (size_t)b * M_ * 64;
    float t1 = 0.f, t2 = 0.f, mn = 1e30f, mx = -1e30f;
#pragma unroll 7
    for (int k = 1; k < K_; k++) {
        int idx = clampi(__shfl(myIdx, k), M_);
        float v = Pgb[(size_t)idx * 64 + lane];
        t1 += v; t2 = fmaf(v, v, t2);
        mn = fminf(mn, v); mx = fmaxf(mx, v);
    }
    size_t o = (size_t)row * 64 + lane;
    T1[o] = t1; T2[o] = t2; Mn[o] = mn; Mx[o] = mx;
}

// ---------------------------------------------------------------- grid KNN D=64 (staged distance) + radix select
DEV void nbr64_body(int blk, const float* __restrict__ g, const float* __restrict__ gT,
                    const float* __restrict__ gn, const float* __restrict__ Pg,
                    int* __restrict__ nbr, float* __restrict__ T1, float* __restrict__ T2,
                    float* __restrict__ Mn, float* __restrict__ Mx,
                    float (*__restrict__ lg)[512], float (*__restrict__ ql)[64],
                    int (*__restrict__ idxb)[64]) {
    int lane = threadIdx.x & 63, w = threadIdx.x >> 6;
    int tid = threadIdx.x;
    int row = blk * 4 + w;
    int b = row >> 9;
    float qn = gn[row];
    const float* gTb = gT + (size_t)b * 64 * M_;
    const float* gnb = gn + b * M_;
    if (tid < 64) {
        const float4* q4 = (const float4*)(g + (size_t)(blk * 4) * 64);
        ((float4*)ql)[tid] = q4[tid];
    }
    float d[8] = {0.f, 0.f, 0.f, 0.f, 0.f, 0.f, 0.f, 0.f};
#pragma clang loop unroll(disable)
    for (int ch = 0; ch < 8; ch++) {
        __syncthreads();
        {
            const float4* src = (const float4*)(gTb + (size_t)ch * 8 * M_);
            float4* dst = (float4*)lg;
#pragma unroll
            for (int i = 0; i < 4; i++) {
                int idx = i * 256 + tid;
                dst[idx] = src[idx];
            }
        }
        __syncthreads();
#pragma unroll
        for (int j = 0; j < 8; j++) {
            float qc = ql[w][ch * 8 + j];   // uniform ds_read (broadcast)
            float4 g0 = *(const float4*)&lg[j][4 * lane];
            float4 g1 = *(const float4*)&lg[j][256 + 4 * lane];
            d[0] = fmaf(qc, g0.x, d[0]); d[1] = fmaf(qc, g0.y, d[1]);
            d[2] = fmaf(qc, g0.z, d[2]); d[3] = fmaf(qc, g0.w, d[3]);
            d[4] = fmaf(qc, g1.x, d[4]); d[5] = fmaf(qc, g1.y, d[5]);
            d[6] = fmaf(qc, g1.z, d[6]); d[7] = fmaf(qc, g1.w, d[7]);
        }
    }
    float4 n0 = *(const float4*)(gnb + 4 * lane);
    float4 n1 = *(const float4*)(gnb + 256 + 4 * lane);
    float dd[8];
    dd[0] = qn + n0.x - 2.f * d[0]; dd[1] = qn + n0.y - 2.f * d[1];
    dd[2] = qn + n0.z - 2.f * d[2]; dd[3] = qn + n0.w - 2.f * d[3];
    dd[4] = qn + n1.x - 2.f * d[4]; dd[5] = qn + n1.y - 2.f * d[5];
    dd[6] = qn + n1.z - 2.f * d[6]; dd[7] = qn + n1.w - 2.f * d[7];
    int mreg[8];
#pragma unroll
    for (int i = 0; i < 8; i++) mreg[i] = (i < 4) ? (4 * lane + i) : (256 + 4 * lane + i - 4);
    select50(dd, mreg, lane, nbr + (size_t)row * K_, idxb[w]);
    int myIdx = idxb[w][lane];
    const float* Pgb = Pg + (size_t)b * M_ * 64;
    float t1 = 0.f, t2 = 0.f, mn = 1e30f, mx = -1e30f;
#pragma unroll 7
    for (int k = 1; k < K_; k++) {
        int idx = clampi(__shfl(myIdx, k), M_);
        float v = Pgb[(size_t)idx * 64 + lane];
        t1 += v; t2 = fmaf(v, v, t2);
        mn = fminf(mn, v); mx = fmaxf(mx, v);
    }
    size_t o = (size_t)row * 64 + lane;
    T1[o] = t1; T2[o] = t2; Mn[o] = mn; Mx[o] = mx;
}

// ---------------------------------------------------------------- fused KNN launches
__global__ __launch_bounds__(256) void k_knn3(
    const float* __restrict__ q, const float* __restrict__ gt, const float* __restrict__ gT3,
    const float* __restrict__ gn, const float* __restrict__ Pg,
    int* __restrict__ nearest, int* __restrict__ nbr, float* __restrict__ T1,
    float* __restrict__ T2, float* __restrict__ Mn, float* __restrict__ Mx) {
    __shared__ int idxb[4][64];
    if (blockIdx.x < BN / 16) nearest3_body(blockIdx.x, q, gt, gn, nearest);
    else nbr3_body(blockIdx.x - BN / 16, gt, gT3, gn, Pg, nbr, T1, T2, Mn, Mx, idxb);
}
__global__ __launch_bounds__(256) void k_knn64(
    const float* __restrict__ q, const float* __restrict__ xgt, const float* __restrict__ gT,
    const float* __restrict__ gn, const float* __restrict__ Pg,
    int* __restrict__ nearest, int* __restrict__ nbr, float* __restrict__ T1,
    float* __restrict__ T2, float* __restrict__ Mn, float* __restrict__ Mx) {
    __shared__ float lg[8][512];   // 16 KB staging panel
    __shared__ float ql[16][64];   // 4 KB q rows
    __shared__ int idxb[4][64];    // 1 KB selected-index rows
    if (blockIdx.x < BN / 16) nearest64_body_v4(blockIdx.x, q, gT, gn, nearest, lg, ql);
    else nbr64_body(blockIdx.x - BN / 16, xgt, gT, gn, Pg, nbr, T1, T2, Mn, Mx, lg, ql, idxb);
}

// ---------------------------------------------------------------- deterministic block stats store
#define STATS_STORE_64(s1v, s2v, partial)                                         \
    {                                                                             \
        __shared__ float r1_[256], r2_[256];                                      \
        r1_[threadIdx.x] = (s1v); r2_[threadIdx.x] = (s2v);                       \
        __syncthreads();                                                          \
        if (threadIdx.x < 64) {                                                   \
            int t_ = threadIdx.x;                                                 \
            float a1_ = r1_[t_] + r1_[t_ + 64] + r1_[t_ + 128] + r1_[t_ + 192];   \
            float a2_ = r2_[t_] + r2_[t_ + 64] + r2_[t_ + 128] + r2_[t_ + 192];   \
            float* sp_ = (partial) + (size_t)blockIdx.x * 128;                    \
            sp_[t_] = a1_; sp_[64 + t_] = a2_;                                    \
        }                                                                         \
    }

// ---------------------------------------------------------------- Pg for stage A (D=3)
__global__ __launch_bounds__(256) void k_pgrid3(const float* __restrict__ g,
                                                const float* __restrict__ W1,
                                                float* __restrict__ Pg) {
    int lane = threadIdx.x & 63;
    int row = blockIdx.x * 4 + __builtin_amdgcn_readfirstlane(threadIdx.x >> 6);
    float c0 = g[row * 3], c1 = g[row * 3 + 1], c2 = g[row * 3 + 2];
    const float* wr = W1 + lane * 6;
    Pg[(size_t)row * 64 + lane] = fmaf(wr[0], c0, fmaf(wr[1], c1, wr[2] * c2));
}

// ---------------------------------------------------------------- fused grid prep (stages B/C)
__global__ __launch_bounds__(256) void k_gridprep(
    const float* __restrict__ xsrc, const int* __restrict__ FPS,
    const float* __restrict__ Wt, float* __restrict__ xgt, float* __restrict__ gT,
    float* __restrict__ gn, float* __restrict__ Pg) {
    int lane = threadIdx.x & 63, w = threadIdx.x >> 6;
    int row = blockIdx.x * 4 + w;
    int b = row >> 9, m = row & 511;
    int src = b * N_ + clampi(FPS[row], N_);
    float ge = xsrc[(size_t)src * 64 + lane];
    xgt[(size_t)row * 64 + lane] = ge;
    gT[((size_t)b * 64 + lane) * M_ + m] = ge;
    float s = 0.f, acc = 0.f;
#pragma unroll
    for (int c = 0; c < 64; c++) {
        float vc = __shfl(ge, c);
        s = fmaf(vc, vc, s);
        acc = fmaf(Wt[c * 64 + lane], vc, acc);
    }
    Pg[(size_t)row * 64 + lane] = acc;
    if (lane == 0) gn[row] = s;
}

// ---------------------------------------------------------------- fused prep + BN stats of y1
template <int D>
__global__ __launch_bounds__(256) void k_prep_stats(
    const float* __restrict__ q, const float* __restrict__ W1,
    const int* __restrict__ nearest, const float* __restrict__ T1,
    const float* __restrict__ T2, float* __restrict__ D0, float* __restrict__ S0,
    float* __restrict__ partial) {
    int lane = threadIdx.x & 63;
    int pt = blockIdx.x * 4 + __builtin_amdgcn_readfirstlane(threadIdx.x >> 6);
    int b = pt >> 12;
    float pa, pb;
    if constexpr (D == 3) {
        float c0 = q[pt * 3], c1 = q[pt * 3 + 1], c2 = q[pt * 3 + 2];
        const float* wr = W1 + lane * 6;
        pa = fmaf(wr[0], c0, fmaf(wr[1], c1, wr[2] * c2));
        pb = fmaf(wr[3], c0, fmaf(wr[4], c1, wr[5] * c2));
    } else {
        float ge = q[(size_t)pt * 64 + lane];
        pa = 0.f; pb = 0.f;
#pragma unroll
        for (int c = 0; c < 64; c++) {
            float sh = __shfl(ge, c);
            pa = fmaf(W1[c * 64 + lane], sh, pa);
            pb = fmaf(W1[(64 + c) * 64 + lane], sh, pb);
        }
    }
    float d0 = pb - pa, s0 = pb;
    size_t t = (size_t)pt * 64 + lane;
    D0[t] = d0;
    S0[t] = s0;
    size_t nr = ((size_t)b * M_ + clampi(nearest[pt], M_)) * 64 + lane;
    float t1 = T1[nr], t2 = T2[nr];
    float s1 = s0 + fmaf(49.f, d0, t1);
    float s2 = fmaf(s0, s0, fmaf(49.f * d0, d0, fmaf(2.f * d0, t1, t2)));
    STATS_STORE_64(s1, s2, partial)
}

// ---------------------------------------------------------------- stage-C output: bn+lrelu(max) exact
__global__ void k_apply0(const float* __restrict__ D0, const float* __restrict__ S0,
                         const int* __restrict__ nearest, const float* __restrict__ Mn,
                         const float* __restrict__ Mx, const float* __restrict__ prm,
                         float* __restrict__ xout) {
    int t = blockIdx.x * 256 + threadIdx.x;
    int pt = t >> 6, o = t & 63;
    int b = pt >> 12;
    size_t nr = ((size_t)b * M_ + clampi(nearest[pt], M_)) * 64 + o;
    float d0 = D0[t], s0 = S0[t];
    float a = prm[o], sh = prm[64 + o];
    float v = a > 0.f ? fmaxf(s0, d0 + Mx[nr]) : fminf(s0, d0 + Mn[nr]);
    xout[t] = lrelu(fmaf(a, v, sh));
}

// ---------------------------------------------------------------- pass1 via MFMA (3-term bf16 split, coalesced gather)
// r9 shell (2 pts/block, 256 thr, 32KB LDS) with a restructured Z-build:
// (1) neighbor ids gathered once into LDS (kills per-thread dependent chain);
// (2) 16 consecutive lanes cooperatively load one 256B ubuf row (8 cache
// lines per load instr instead of 64 -> ~4-8x less TA address-serialization).
// Same formulas/order/LDS layout -> bit-identical outputs vs r9.
__global__ __launch_bounds__(256) void k_pass1_mfma(
    const float* __restrict__ ub, const float* __restrict__ D0,
    const float* __restrict__ S0, const int* __restrict__ nearest,
    const int* __restrict__ nbr, const float* __restrict__ prm1,
    const u16* __restrict__ wf, float* __restrict__ partial,
    float* __restrict__ mn_out, float* __restrict__ mx_out) {
    __shared__ u16 Zs[2][2][4096];   // 32 KB; first 1KB reused as ls1/ls2 post-MFMA
    __shared__ int idxl[2][64];
    float* ls1 = (float*)&Zs[0][0][0];
    float* ls2 = ls1 + 128;
    int l = threadIdx.x & 63;
    int w = threadIdx.x >> 6;
    int wp = w >> 1, nh = w & 1;     // wave's point, wave's o-half
    bf8v whi[2][2], wlo[2][2];
#pragma unroll
    for (int nt = 0; nt < 2; nt++)
#pragma unroll
        for (int s = 0; s < 2; s++) {
            int fi = (((nh * 2 + nt) * 2 + s) * 64 + l) * 8;
            whi[nt][s] = *(const bf8v*)(wf + fi);
            wlo[nt][s] = *(const bf8v*)(wf + 4096 + fi);
        }
    // ---- neighbor-id gather: threads 0..127, one id each ----
    if (threadIdx.x < 128) {
        int p2 = threadIdx.x >> 6, k = threadIdx.x & 63;
        int pt2 = blockIdx.x * 2 + p2, b2 = pt2 >> 12;
        int nr = clampi(nearest[pt2], M_);
        idxl[p2][k] = (k >= 1 && k < K_)
                          ? clampi(nbr[((size_t)b2 * M_ + nr) * K_ + k], M_) : 0;
    }
    __syncthreads();
    // ---- Z build: per point, group g=tt>>4 owns row k=s*8+g; lane j=tt&15 owns cols j*4.. ----
    {
        int tt = threadIdx.x & 127;
        int p = threadIdx.x >> 7;
        int pt = blockIdx.x * 2 + p, b = pt >> 12;
        int g = tt >> 4, j = tt & 15;
        char* zh = (char*)&Zs[p][0][0];
        char* zl = (char*)&Zs[p][1][0];
        float4 a = ((const float4*)prm1)[j];
        float4 sh4 = ((const float4*)(prm1 + 64))[j];
        float4 dv = ((const float4*)(D0 + (size_t)pt * 64))[j];
        const float* ubb = ub + (size_t)b * M_ * 64;
#pragma unroll
        for (int s = 0; s < 8; s++) {
            int k = s * 8 + g;
            float4 u, d = dv;
            if (k == 0) {   // center row: fold bn into u, d=0 (bit-exact old path)
                float4 s0 = ((const float4*)(S0 + (size_t)pt * 64))[j];
                u.x = fmaf(a.x, s0.x, sh4.x); u.y = fmaf(a.y, s0.y, sh4.y);
                u.z = fmaf(a.z, s0.z, sh4.z); u.w = fmaf(a.w, s0.w, sh4.w);
                d.x = 0.f; d.y = 0.f; d.z = 0.f; d.w = 0.f;
            } else {
                int idx = idxl[p][k];
                u = ((const float4*)(ubb + (size_t)idx * 64))[j];
            }
            float z0 = lrelu(fmaf(a.x, d.x, u.x));
            float z1 = lrelu(fmaf(a.y, d.y, u.y));
            float z2 = lrelu(fmaf(a.z, d.z, u.z));
            float z3 = lrelu(fmaf(a.w, d.w, u.w));
            if (k >= K_) { z0 = 0.f; z1 = 0.f; z2 = 0.f; z3 = 0.f; }
            unsigned h01 = cvtpk(z0, z1), h23 = cvtpk(z2, z3);
            float r0 = z0 - __uint_as_float(h01 << 16);
            float r1 = z1 - __uint_as_float(h01 & 0xFFFF0000u);
            float r2 = z2 - __uint_as_float(h23 << 16);
            float r3 = z3 - __uint_as_float(h23 & 0xFFFF0000u);
            unsigned l01 = cvtpk(r0, r1), l23 = cvtpk(r2, r3);
            int ad = k * 128 + ((j * 8) ^ ((k & 7) << 4));   // same swizzled layout
            *(uint2*)(zh + ad) = make_uint2(h01, h23);
            *(uint2*)(zl + ad) = make_uint2(l01, l23);
        }
    }
    __syncthreads();
    // ---- MFMA: wave computes Y[64k x 32o] for its point ----
    int pt = blockIdx.x * 2 + wp;
    const char* zh = (const char*)&Zs[wp][0][0];
    const char* zl = (const char*)&Zs[wp][1][0];
    f4v acc[4][2] = {};
#pragma unroll
    for (int s = 0; s < 2; s++) {
        bf8v ah[4], al[4];
#pragma unroll
        for (int m = 0; m < 4; m++) {
            int row = m * 16 + (l & 15);
            int ad = row * 128 + (((s * 64) + ((l >> 4) * 16)) ^ ((row & 7) << 4));
            ah[m] = *(const bf8v*)(zh + ad);
            al[m] = *(const bf8v*)(zl + ad);
        }
#pragma unroll
        for (int m = 0; m < 4; m++)
#pragma unroll
            for (int nt = 0; nt < 2; nt++) {
                acc[m][nt] = __builtin_amdgcn_mfma_f32_16x16x32_bf16(ah[m], whi[nt][s], acc[m][nt], 0, 0, 0);
                acc[m][nt] = __builtin_amdgcn_mfma_f32_16x16x32_bf16(al[m], whi[nt][s], acc[m][nt], 0, 0, 0);
                acc[m][nt] = __builtin_amdgcn_mfma_f32_16x16x32_bf16(ah[m], wlo[nt][s], acc[m][nt], 0, 0, 0);
            }
    }
    __syncthreads();   // Zs reads complete; ls1/ls2 alias region now safe to write
    int rg = (l >> 4) * 4;
#pragma unroll
    for (int nt = 0; nt < 2; nt++) {
        float s1 = 0.f, s2 = 0.f, mn = 1e30f, mx = -1e30f;
#pragma unroll
        for (int m = 0; m < 4; m++)
#pragma unroll
            for (int i = 0; i < 4; i++) {
                int kk = m * 16 + rg + i;
                float v = acc[m][nt][i];
                if (kk < K_) { s1 += v; s2 = fmaf(v, v, s2); mn = fminf(mn, v); mx = fmaxf(mx, v); }
            }
        for (int off = 16; off <= 32; off <<= 1) {
            s1 += __shfl_xor(s1, off); s2 += __shfl_xor(s2, off);
            mn = fminf(mn, __shfl_xor(mn, off)); mx = fmaxf(mx, __shfl_xor(mx, off));
        }
        if (l < 16) {
            int o = nh * 32 + nt * 16 + l;
            mn_out[(size_t)pt * 64 + o] = mn;
            mx_out[(size_t)pt * 64 + o] = mx;
            ls1[wp * 64 + o] = s1;
            ls2[wp * 64 + o] = s2;
        }
    }
    __syncthreads();
    if (threadIdx.x < 64) {
        int t = threadIdx.x;
        float* sp = partial + (size_t)blockIdx.x * 128;
        sp[t] = ls1[t] + ls1[64 + t];
        sp[64 + t] = ls2[t] + ls2[64 + t];
    }
}

// ---------------------------------------------------------------- apply bn+lrelu to min/max (exact)
__global__ void k_apply(const float* __restrict__ mn, const float* __restrict__ mx,
                        const float* __restrict__ prm, float* __restrict__ xout) {
    int t = blockIdx.x * 256 + threadIdx.x;
    int o = t & 63;
    float a = prm[o], sh = prm[64 + o];
    float v = a > 0.f ? mx[t] : mn[t];
    xout[t] = lrelu(fmaf(a, v, sh));
}

// ---------------------------------------------------------------- fused reduce+finalize (32 blocks)
template <int NP, int O>
__global__ __launch_bounds__(256) void k_redfin(
    const float* __restrict__ partial, double* __restrict__ red,
    int* __restrict__ counter, int C,
    const float* __restrict__ g, const float* __restrict__ bt,
    float* __restrict__ prm) {
    constexpr int VALS = 2 * O;
    constexpr int G = NP / 32;
    int b = blockIdx.x;   // 32 blocks
    for (int v = threadIdx.x; v < VALS; v += 256) {
        const float* p = partial + (size_t)b * G * VALS + v;
        double s = 0.0;
        for (int k = 0; k < G; k++) s += p[(size_t)k * VALS];
        red[(size_t)b * VALS + v] = s;
    }
    __threadfence();
    __syncthreads();
    __shared__ bool isLast;
    if (threadIdx.x == 0) isLast = (atomicAdd(counter, 1) == 31);
    __syncthreads();
    if (!isLast) return;
    __threadfence();
    for (int o = threadIdx.x; o < O; o += 256) {
        double s1 = 0.0, s2 = 0.0;
#pragma unroll
        for (int k = 0; k < 32; k++) {
            s1 += red[(size_t)k * VALS + o];
            s2 += red[(size_t)k * VALS + O + o];
        }
        double m = s1 / C, var = s2 / C - m * m;
        if (var < 0) var = 0;
        float sc = g[o] / sqrtf((float)var + EPS_);
        prm[o] = sc;
        prm[O + o] = bt[o] - (float)m * sc;
    }
}

// ---------------------------------------------------------------- W6 conv (192->512), Wt-coalesced, 4-row tiles
__global__ __launch_bounds__(256) void k_conv_w6(
    const float* __restrict__ x1gt, const float* __restrict__ x2gt,
    const float* __restrict__ x3t, const int* __restrict__ FPS,
    const float* __restrict__ W6t, float* __restrict__ y6, float* __restrict__ partial) {
    __shared__ float vl[4][192];
    int b = blockIdx.x / 128;
    int m0 = (blockIdx.x % 128) * 4;
    for (int i = threadIdx.x; i < 4 * 192; i += 256) {
        int mi = i / 192, c = i % 192;
        float v;
        if (c < 128) {
            const float* src = c < 64 ? x1gt : x2gt;
            v = src[((size_t)b * M_ + m0 + mi) * 64 + (c & 63)];
        } else {
            int s = b * N_ + clampi(FPS[b * M_ + m0 + mi], N_);
            v = x3t[(size_t)s * 64 + (c - 128)];
        }
        vl[mi][c] = v;
    }
    __syncthreads();
    float acc0[4] = {0}, acc1[4] = {0};
    int o0 = threadIdx.x, o1 = threadIdx.x + 256;
    for (int c = 0; c < 192; c++) {
        float w0 = W6t[c * 512 + o0];
        float w1 = W6t[c * 512 + o1];
#pragma unroll
        for (int m = 0; m < 4; m++) { float v = vl[m][c]; acc0[m] = fmaf(w0, v, acc0[m]); acc1[m] = fmaf(w1, v, acc1[m]); }
    }
    float s1a = 0, s2a = 0, s1b = 0, s2b = 0;
    for (int m = 0; m < 4; m++) {
        float ya = acc0[m], yb = acc1[m];
        y6[((size_t)b * M_ + m0 + m) * 512 + o0] = ya;
        y6[((size_t)b * M_ + m0 + m) * 512 + o1] = yb;
        s1a += ya; s2a = fmaf(ya, ya, s2a); s1b += yb; s2b = fmaf(yb, yb, s2b);
    }
    float* sp = partial + (size_t)blockIdx.x * 1024;
    sp[o0] = s1a; sp[512 + o0] = s2a;
    sp[o1] = s1b; sp[512 + o1] = s2b;
}

// ---------------------------------------------------------------- bn6+lrelu+max over M (128 blocks)
__global__ void k_maxM(const float* __restrict__ y6, const float* __restrict__ prm,
                       float* __restrict__ xgmax) {
    int blk = blockIdx.x;            // B_*64
    int b = blk >> 6;
    int obase = (blk & 63) << 3;
    int o = obase + (threadIdx.x & 7);
    int mg = threadIdx.x >> 3;       // 32 m-groups
    float a = prm[o], sh = prm[512 + o];
    float mx = -1e30f;
    for (int m = mg; m < M_; m += 32)
        mx = fmaxf(mx, lrelu(fmaf(a, y6[((size_t)b * M_ + m) * 512 + o], sh)));
    __shared__ float red[256];
    red[threadIdx.x] = mx;
    __syncthreads();
    for (int s = 128; s >= 8; s >>= 1) {
        if (threadIdx.x < s) red[threadIdx.x] = fmaxf(red[threadIdx.x], red[threadIdx.x + s]);
        __syncthreads();
    }
    if (threadIdx.x < 8) xgmax[b * 512 + obase + threadIdx.x] = red[threadIdx.x];
}

// ---------------------------------------------------------------- P7: wave per output (fixed xor tree)
__global__ __launch_bounds__(256) void k_p7(const float* __restrict__ xgmax,
                                            const float* __restrict__ W7,
                                            float* __restrict__ p7) {
    int lane = threadIdx.x & 63, w = threadIdx.x >> 6;
    int t = blockIdx.x * 4 + w;     // 0..255
    int b = t >> 7, o = t & 127;
    float acc = 0.f;
#pragma unroll
    for (int j = 0; j < 8; j++) {
        int c = j * 64 + lane;
        acc = fmaf(W7[o * 704 + c], xgmax[b * 512 + c], acc);
    }
    for (int off = 32; off; off >>= 1) acc += __shfl_xor(acc, off);
    if (lane == 0) p7[t] = acc;
}

// ---------------------------------------------------------------- W7 conv (192-col part) via MFMA, 16 items/block
__global__ __launch_bounds__(256) void k_conv_w7m(
    const float* __restrict__ x1t, const float* __restrict__ x2t,
    const float* __restrict__ x3t, const float* __restrict__ p7,
    const u16* __restrict__ wf7, float* __restrict__ y7, float* __restrict__ partial) {
    __shared__ u16 Zh[16][200], Zl[16][200];   // 12.5 KB
    int tid = threadIdx.x;
    int l = tid & 63, w = tid >> 6;
    int item0 = blockIdx.x * 16;
    int b = blockIdx.x >> 8;                    // 512 blocks, 256 per batch
    bf8v wh[2][6], wl[2][6];
#pragma unroll
    for (int nt = 0; nt < 2; nt++)
#pragma unroll
        for (int s = 0; s < 6; s++) {
            int fi = (((2 * w + nt) * 6 + s) * 64 + l) * 8;
            wh[nt][s] = *(const bf8v*)(wf7 + fi);
            wl[nt][s] = *(const bf8v*)(wf7 + 24576 + fi);
        }
    {
        int item = tid >> 4, seg = tid & 15;
        if (seg < 12) {
            const float* sp_;
            size_t base = (size_t)(item0 + item) * 64;
            if (seg < 4) sp_ = x1t + base + seg * 16;
            else if (seg < 8) sp_ = x2t + base + (seg - 4) * 16;
            else sp_ = x3t + base + (seg - 8) * 16;
            float f[16];
#pragma unroll
            for (int i = 0; i < 4; i++) {
                float4 v = ((const float4*)sp_)[i];
                f[4 * i] = v.x; f[4 * i + 1] = v.y; f[4 * i + 2] = v.z; f[4 * i + 3] = v.w;
            }
            unsigned hp[8], lp[8];
#pragma unroll
            for (int e = 0; e < 8; e++) {
                unsigned h = cvtpk(f[2 * e], f[2 * e + 1]);
                float r0 = f[2 * e] - __uint_as_float(h << 16);
                float r1 = f[2 * e + 1] - __uint_as_float(h & 0xFFFF0000u);
                hp[e] = h;
                lp[e] = cvtpk(r0, r1);
            }
            uint4* dh = (uint4*)&Zh[item][seg * 16];
            uint4* dl = (uint4*)&Zl[item][seg * 16];
            dh[0] = make_uint4(hp[0], hp[1], hp[2], hp[3]);
            dh[1] = make_uint4(hp[4], hp[5], hp[6], hp[7]);
            dl[0] = make_uint4(lp[0], lp[1], lp[2], lp[3]);
            dl[1] = make_uint4(lp[4], lp[5], lp[6], lp[7]);
        }
    }
    __syncthreads();
    f4v acc[2] = {};
#pragma unroll
    for (int s = 0; s < 6; s++) {
        int row = l & 15, col = s * 32 + (l >> 4) * 8;
        bf8v ah = *(const bf8v*)&Zh[row][col];
        bf8v al = *(const bf8v*)&Zl[row][col];
#pragma unroll
        for (int nt = 0; nt < 2; nt++) {
            acc[nt] = __builtin_amdgcn_mfma_f32_16x16x32_bf16(ah, wh[nt][s], acc[nt], 0, 0, 0);
            acc[nt] = __builtin_amdgcn_mfma_f32_16x16x32_bf16(al, wh[nt][s], acc[nt], 0, 0, 0);
            acc[nt] = __builtin_amdgcn_mfma_f32_16x16x32_bf16(ah, wl[nt][s], acc[nt], 0, 0, 0);
        }
    }
#pragma unroll
    for (int nt = 0; nt < 2; nt++) {
        int o = (2 * w + nt) * 16 + (l & 15);
        float pv = p7[b * 128 + o];
        float s1 = 0.f, s2 = 0.f;
#pragma unroll
        for (int i = 0; i < 4; i++) {
            int item = (l >> 4) * 4 + i;
            float yv = pv + acc[nt][i];
            y7[(size_t)(item0 + item) * 128 + o] = yv;
            s1 += yv; s2 = fmaf(yv, yv, s2);
        }
        for (int off = 16; off <= 32; off <<= 1) {
            s1 += __shfl_xor(s1, off);
            s2 += __shfl_xor(s2, off);
        }
        if (l < 16) {
            float* sp = partial + (size_t)blockIdx.x * 256;
            sp[o] = s1;
            sp[128 + o] = s2;
        }
    }
}

// ---------------------------------------------------------------- W8 conv (128->64), Wt-coalesced
__global__ __launch_bounds__(256) void k_conv_w8(
    const float* __restrict__ y7, const float* __restrict__ prm7,
    const float* __restrict__ W8t, float* __restrict__ y8, float* __restrict__ partial) {
    int lane = threadIdx.x & 63;
    int item = blockIdx.x * 4 + (threadIdx.x >> 6);
    float W0[64], W1r[64];
#pragma unroll
    for (int c = 0; c < 64; c++) {
        W0[c] = W8t[c * 64 + lane];
        W1r[c] = W8t[(64 + c) * 64 + lane];
    }
    float a0 = prm7[lane], sh0 = prm7[128 + lane];
    float a1 = prm7[64 + lane], sh1 = prm7[128 + 64 + lane];
    float z0 = lrelu(fmaf(a0, y7[(size_t)item * 128 + lane], sh0));
    float z1 = lrelu(fmaf(a1, y7[(size_t)item * 128 + 64 + lane], sh1));
    float acc = 0.f;
#pragma unroll
    for (int c = 0; c < 64; c++) {
        acc = fmaf(W0[c], __shfl(z0, c), acc);
        acc = fmaf(W1r[c], __shfl(z1, c), acc);
    }
    y8[(size_t)item * 64 + lane] = acc;
    STATS_STORE_64(acc, acc * acc, partial)
}

// ---------------------------------------------------------------- final: bn8+lrelu, W9t -> out
__global__ __launch_bounds__(256) void k_final(
    const float* __restrict__ y8, const float* __restrict__ prm8,
    const float* __restrict__ W9t, void* __restrict__ out, const int* __restrict__ flag) {
    __shared__ float zl[2][64];
    int item0 = blockIdx.x * 2;
    if (threadIdx.x < 128) {
        int it = threadIdx.x >> 6, c = threadIdx.x & 63;
        float z = fmaf(prm8[c], y8[(size_t)(item0 + it) * 64 + c], prm8[64 + c]);
        zl[it][c] = lrelu(z);
    }
    __syncthreads();
    int it = threadIdx.x >> 7, o = threadIdx.x & 127;
    float acc = 0.f;
#pragma unroll
    for (int c = 0; c < 64; c++) acc = fmaf(W9t[c * 128 + o], zl[it][c], acc);
    size_t oi = (size_t)(item0 + it) * 128 + o;
    if (*flag) ((bf16*)out)[oi] = __float2bfloat16(acc);
    else ((float*)out)[oi] = acc;
}

// ---------------------------------------------------------------- host
extern "C" void kernel_launch(void* const* d_in, const int* in_sizes, int n_in,
                              void* d_out, int out_size, void* d_ws, size_t ws_size,
                              hipStream_t stream) {
    (void)in_sizes; (void)n_in; (void)out_size; (void)ws_size;
    const void* x = d_in[0];
    const void* xgrid = d_in[1];
    const int* FPS = (const int*)d_in[2];

    char* ws = (char*)d_ws;
    size_t off = 0;
    auto alloc = [&](size_t bytes) -> char* {
        char* p = ws + off;
        off = (off + bytes + 255) & ~(size_t)255;
        return p;
    };
    int* flag       = (int*)alloc(256);
    int* counters   = (int*)alloc(256);
    float* partials = (float*)alloc((size_t)4096 * 128 * sizeof(float));   // 2 MB (pass1 grid = 4096)
    double* redbuf  = (double*)alloc(32 * 1024 * sizeof(double));  // 256 KB
    float* prm      = (float*)alloc(8 * 1024 * sizeof(float));
    static const int wsz[9] = {384, 4096, 8192, 4096, 8192, 98304, 90112, 8192, 8192};
    static const int dims[8] = {64, 64, 64, 64, 64, 512, 128, 64};
    float* cW[9];
    for (int i = 0; i < 9; i++) cW[i] = (float*)alloc((size_t)wsz[i] * 4);
    float* cG[8];
    float* cB[8];
    for (int j = 0; j < 8; j++) {
        cG[j] = (float*)alloc((size_t)dims[j] * 4);
        cB[j] = (float*)alloc((size_t)dims[j] * 4);
    }
    float* W6t  = (float*)alloc((size_t)512 * 192 * 4);
    float* W7vt = (float*)alloc((size_t)128 * 192 * 4);
    float* W8t  = (float*)alloc((size_t)64 * 128 * 4);
    float* W9t  = (float*)alloc((size_t)128 * 64 * 4);
    float* W3t  = (float*)alloc((size_t)64 * 128 * 4);
    float* W5t  = (float*)alloc((size_t)64 * 128 * 4);
    u16* wf2    = (u16*)alloc((size_t)8192 * 2);    // W2 MFMA frags hi+lo
    u16* wf4    = (u16*)alloc((size_t)8192 * 2);    // W4 MFMA frags hi+lo
    u16* wf7    = (u16*)alloc((size_t)49152 * 2);   // W7 MFMA frags hi+lo
    float* xt    = (float*)alloc((size_t)BN * 3 * 4);
    float* gt    = (float*)alloc((size_t)BM * 3 * 4);
    float* gT3   = (float*)alloc((size_t)B_ * 3 * M_ * 4);
    float* gn    = (float*)alloc((size_t)BM * 4);
    int* nearest = (int*)alloc((size_t)BN * 4);
    int* nbr     = (int*)alloc((size_t)BM * K_ * 4);
    float* Pg    = (float*)alloc((size_t)BM * 64 * 4);
    float* ubuf  = (float*)alloc((size_t)BM * 64 * 4);
    float* x1t   = (float*)alloc((size_t)BN * 64 * 4);
    float* x2t   = (float*)alloc((size_t)BN * 64 * 4);
    float* x3t   = (float*)alloc((size_t)BN * 64 * 4);
    float* x1gt  = (float*)alloc((size_t)BM * 64 * 4);
    float* x2gt  = (float*)alloc((size_t)BM * 64 * 4);
    float* gT64  = (float*)alloc((size_t)B_ * 64 * M_ * 4);
    float* y6    = (float*)alloc((size_t)BM * 512 * 4);
    float* xgmax = (float*)alloc((size_t)B_ * 512 * 4);
    float* p7    = (float*)alloc((size_t)B_ * 128 * 4);
    float* y7    = (float*)alloc((size_t)BN * 128 * 4);
    float* y8    = (float*)alloc((size_t)BN * 64 * 4);
    // Aliases (lifetimes verified; same layout as passing rounds):
    float* D0b = y7;
    float* S0b = y7 + (size_t)BN * 64;
    float* mnb = y8;
    float* mxb = y6;
    float* T1b = y6;
    float* T2b = y6 + (size_t)BM * 64;
    float* Mnb = y6 + (size_t)2 * BM * 64;
    float* Mxb = y6 + (size_t)3 * BM * 64;

    hipMemsetAsync(counters, 0, 8 * sizeof(int), stream);
    k_detect<<<1, 256, 0, stream>>>((const unsigned short*)x, flag);

    CvtArgs ca;
    for (int i = 0; i < 9; i++) ca.d[i] = {d_in[3 + i], cW[i], wsz[i]};
    for (int j = 0; j < 8; j++) {
        ca.d[9 + 2 * j]     = {d_in[12 + 2 * j], cG[j], dims[j]};
        ca.d[9 + 2 * j + 1] = {d_in[13 + 2 * j], cB[j], dims[j]};
    }
    k_convert<<<dim3(384, 25), 256, 0, stream>>>(ca, flag);
    CvtTArgs ct;
    ct.d[0] = {d_in[8],  W6t,  512, 192, 192, 0};    // W6
    ct.d[1] = {d_in[9],  W7vt, 128, 192, 704, 512};  // W7 variable cols
    ct.d[2] = {d_in[10], W8t,  64, 128, 128, 0};     // W8
    ct.d[3] = {d_in[11], W9t,  128, 64, 64, 0};      // W9
    ct.d[4] = {d_in[5],  W3t,  64, 128, 128, 0};     // W3 transposed (prep/gridprep)
    ct.d[5] = {d_in[7],  W5t,  64, 128, 128, 0};     // W5 transposed
    k_convT<<<dim3(384, 6), 256, 0, stream>>>(ct, flag);
    k_wfrag<<<dim3(16, 2), 256, 0, stream>>>(cW[1], cW[3], wf2, wf4);
    k_wfrag7<<<96, 256, 0, stream>>>(W7vt, wf7);
    k_transpose<<<(BN * 3 + BM + 255) / 256, 256, 0, stream>>>(x, xgrid, flag, xt, gt, gT3, gn);

    const int PG = BN / 4;         // wave-per-point grids (2048)
    const int EW = BN * 64 / 256;  // elementwise grids
    const int CK = BN * K_;
    const int KNNG = BN / 16 + BM / 4;   // 512 nearest blocks + 256 nbr blocks
    const int UBG = BM * 64 / 256;       // ubuf grid (256)

    // ---- stage A (D=3, W1,W2) ----
    k_pgrid3<<<BM / 4, 256, 0, stream>>>(gt, cW[0], Pg);
    k_knn3<<<KNNG, 256, 0, stream>>>(xt, gt, gT3, gn, Pg, nearest, nbr, T1b, T2b, Mnb, Mxb);
    k_prep_stats<3><<<PG, 256, 0, stream>>>(xt, cW[0], nearest, T1b, T2b, D0b, S0b, partials);
    k_redfin<2048, 64><<<32, 256, 0, stream>>>(partials, redbuf, counters + 0, CK, cG[0], cB[0], prm + 0 * 1024);
    k_ubuf<<<UBG, 256, 0, stream>>>(Pg, prm + 0 * 1024, ubuf);
    k_pass1_mfma<<<BN / 2, 256, 0, stream>>>(ubuf, D0b, S0b, nearest, nbr, prm + 0 * 1024, wf2, partials, mnb, mxb);
    k_redfin<4096, 64><<<32, 256, 0, stream>>>(partials, redbuf, counters + 1, CK, cG[1], cB[1], prm + 1 * 1024);
    k_apply<<<EW, 256, 0, stream>>>(mnb, mxb, prm + 1 * 1024, x1t);

    // ---- stage B (D=64, W3,W4) ----
    k_gridprep<<<BM / 4, 256, 0, stream>>>(x1t, FPS, W3t, x1gt, gT64, gn, Pg);
    k_knn64<<<KNNG, 256, 0, stream>>>(x1t, x1gt, gT64, gn, Pg, nearest, nbr, T1b, T2b, Mnb, Mxb);
    k_prep_stats<64><<<PG, 256, 0, stream>>>(x1t, W3t, nearest, T1b, T2b, D0b, S0b, partials);
    k_redfin<2048, 64><<<32, 256, 0, stream>>>(partials, redbuf, counters + 2, CK, cG[2], cB[2], prm + 2 * 1024);
    k_ubuf<<<UBG, 256, 0, stream>>>(Pg, prm + 2 * 1024, ubuf);
    k_pass1_mfma<<<BN / 2, 256, 0, stream>>>(ubuf, D0b, S0b, nearest, nbr, prm + 2 * 1024, wf4, partials, mnb, mxb);
    k_redfin<4096, 64><<<32, 256, 0, stream>>>(partials, redbuf, counters + 3, CK, cG[3], cB[3], prm + 3 * 1024);
    k_apply<<<EW, 256, 0, stream>>>(mnb, mxb, prm + 3 * 1024, x2t);

    // ---- stage C (D=64, W5 single conv) ----
    k_gridprep<<<BM / 4, 256, 0, stream>>>(x2t, FPS, W5t, x2gt, gT64, gn, Pg);
    k_knn64<<<KNNG, 256, 0, stream>>>(x2t, x2gt, gT64, gn, Pg, nearest, nbr, T1b, T2b, Mnb, Mxb);
    k_prep_stats<64><<<PG, 256, 0, stream>>>(x2t, W5t, nearest, T1b, T2b, D0b, S0b, partials);
    k_redfin<2048, 64><<<32, 256, 0, stream>>>(partials, redbuf, counters + 4, CK, cG[4], cB[4], prm + 4 * 1024);
    k_apply0<<<EW, 256, 0, stream>>>(D0b, S0b, nearest, Mnb, Mxb, prm + 4 * 1024, x3t);

    // ---- global MLP tail ----
    k_conv_w6<<<BM / 4, 256, 0, stream>>>(x1gt, x2gt, x3t, FPS, W6t, y6, partials);
    k_redfin<256, 512><<<32, 256, 0, stream>>>(partials, redbuf, counters + 5, BM, cG[5], cB[5], prm + 5 * 1024);
    k_maxM<<<B_ * 64, 256, 0, stream>>>(y6, prm + 5 * 1024, xgmax);
    k_p7<<<64, 256, 0, stream>>>(xgmax, cW[6], p7);
    k_conv_w7m<<<BN / 16, 256, 0, stream>>>(x1t, x2t, x3t, p7, wf7, y7, partials);
    k_redfin<512, 128><<<32, 256, 0, stream>>>(partials, redbuf, counters + 6, BN, cG[6], cB[6], prm + 6 * 1024);
    k_conv_w8<<<BN / 4, 256, 0, stream>>>(y7, prm + 6 * 1024, W8t, y8, partials);
    k_redfin<2048, 64><<<32, 256, 0, stream>>>(partials, redbuf, counters + 7, BN, cG[7], cB[7], prm + 7 * 1024);
    k_final<<<BN / 2, 256, 0, stream>>>(y8, prm + 7 * 1024, W9t, d_out, flag);
}

// Round 13
// 386.415 us; speedup vs baseline: 1.1087x; 1.0142x over previous
//
#include <hip/hip_runtime.h>
#include <hip/hip_bf16.h>

#define DEV __device__ __forceinline__
using bf16 = __hip_bfloat16;
using u16 = unsigned short;
using u64 = unsigned long long;

static constexpr int B_ = 2, N_ = 4096, M_ = 512, K_ = 50;
static constexpr int BN = B_ * N_;   // 8192 points
static constexpr int BM = B_ * M_;   // 1024 grid points
static constexpr float EPS_ = 1e-5f;

DEV float lrelu(float z) { return z < 0.f ? 0.2f * z : z; }
DEV int clampi(int v, int hi) { return ((unsigned)v < (unsigned)hi) ? v : 0; }

// bf16 split helpers (RNE, matches __float2bfloat16 for normals)
DEV u16 f2bfu(float f) {
    unsigned u = __float_as_uint(f);
    return (u16)((u + 0x7fffu + ((u >> 16) & 1u)) >> 16);
}
DEV float bfu2f(u16 h) { return __uint_as_float((unsigned)h << 16); }
// packed f32x2 -> bf16x2; hw round mode; 1-ulp diffs absorbed by lo plane.
DEV unsigned cvtpk(float a, float b) {
    unsigned r;
    asm("v_cvt_pk_bf16_f32 %0, %1, %2" : "=v"(r) : "v"(a), "v"(b));
    return r;
}

typedef short bf8v __attribute__((ext_vector_type(8)));   // 8 bf16 (4 VGPRs)
typedef float f4v __attribute__((ext_vector_type(4)));    // MFMA C/D

// ---------------------------------------------------------------- dtype detect
__global__ void k_detect(const unsigned short* __restrict__ xw, int* __restrict__ flag) {
    int t = threadIdx.x;
    int cnt = 0;
    for (int i = t; i < 4096; i += 256) {
        int e = (xw[i] >> 7) & 0xFF;
        if (e >= 100 && e <= 140) cnt++;
    }
    __shared__ int sh[256];
    sh[t] = cnt;
    __syncthreads();
    for (int s = 128; s; s >>= 1) { if (t < s) sh[t] += sh[t + s]; __syncthreads(); }
    if (t == 0) *flag = (sh[0] >= 3300) ? 1 : 0;
}

DEV float rdval(const void* p, size_t i, int isbf) {
    return isbf ? __bfloat162float(((const bf16*)p)[i]) : ((const float*)p)[i];
}

// ---------------------------------------------------------------- fused setup (convert/convT/wfrag/wfrag7/transpose)
// All branches depend only on raw inputs + flag -> one launch replaces 5.
// wfrag/wfrag7 read RAW weights with inline conversion (identical float ->
// identical fragments vs the old convert-then-frag path).
struct CvtDesc { const void* src; float* dst; int n; };
struct CvtT { const void* src; float* dst; int O; int C; int stride; int off; };
struct SetupArgs { CvtDesc d[25]; CvtT t[6]; };

__global__ __launch_bounds__(256) void k_setup(
    SetupArgs a, const void* __restrict__ W2r, const void* __restrict__ W4r,
    const void* __restrict__ W7r, u16* __restrict__ wf2, u16* __restrict__ wf4,
    u16* __restrict__ wf7, const void* __restrict__ x, const void* __restrict__ xg,
    const int* __restrict__ flag, float* __restrict__ xt, float* __restrict__ gt,
    float* __restrict__ gT3, float* __restrict__ gn) {
    int y = blockIdx.y;
    int isbf = *flag;
    int gi = blockIdx.x * 256 + threadIdx.x;
    if (y < 25) {                     // param convert
        CvtDesc dd = a.d[y];
        if (gi < dd.n) dd.dst[gi] = rdval(dd.src, gi, isbf);
    } else if (y < 31) {              // transposed weight copies
        CvtT dd = a.t[y - 25];
        if (gi < dd.O * dd.C) {
            int c = gi / dd.O, o = gi % dd.O;
            dd.dst[gi] = rdval(dd.src, (size_t)o * dd.stride + dd.off + c, isbf);
        }
    } else if (y == 31 || y == 32) {  // W2/W4 MFMA fragments (raw read)
        const void* W = (y == 31) ? W2r : W4r;
        u16* f = (y == 31) ? wf2 : wf4;
        if (gi < 4096) {
            int j = gi & 7, l = (gi >> 3) & 63, s = (gi >> 9) & 1, n = (gi >> 10) & 3;
            int o = n * 16 + (l & 15);
            int c = s * 32 + (l >> 4) * 8 + j;
            float v = rdval(W, (size_t)o * 64 + c, isbf);
            u16 hi = f2bfu(v);
            u16 lo = f2bfu(v - bfu2f(hi));
            f[gi] = hi;
            f[4096 + gi] = lo;
        }
    } else if (y == 33) {             // W7 (192-col part) MFMA fragments (raw read)
        if (gi < 24576) {
            int j = gi & 7, l = (gi >> 3) & 63;
            int rest = gi >> 9;
            int s = rest % 6, ot = rest / 6;
            int o = ot * 16 + (l & 15);
            int c = s * 32 + (l >> 4) * 8 + j;
            float v = rdval(W7r, (size_t)o * 704 + 512 + c, isbf);
            u16 hi = f2bfu(v);
            u16 lo = f2bfu(v - bfu2f(hi));
            wf7[gi] = hi;
            wf7[24576 + gi] = lo;
        }
    } else {                          // y == 34: input transpose + grid norms
        int idx = gi;
        if (idx < BN * 3) {
            int c = idx / BN, i = idx % BN;
            int b = i / N_, n = i % N_;
            xt[i * 3 + c] = rdval(x, (size_t)(b * 3 + c) * N_ + n, isbf);
        } else {
            int r = idx - BN * 3;
            if (r < BM) {
                int b = r / M_, m = r % M_;
                float s = 0.f;
                for (int c = 0; c < 3; c++) {
                    float v = rdval(xg, (size_t)(b * 3 + c) * M_ + m, isbf);
                    gt[r * 3 + c] = v;
                    gT3[(b * 3 + c) * M_ + m] = v;
                    s = fmaf(v, v, s);
                }
                gn[r] = s;
            }
        }
    }
}

// ---------------------------------------------------------------- nearest D=3 body
DEV void nearest3_body(int blk, const float* __restrict__ q, const float* __restrict__ gt,
                       const float* __restrict__ gn, int* __restrict__ nearest) {
    int sub = threadIdx.x & 15;
    int pt = blk * 16 + (threadIdx.x >> 4);
    int b = pt >> 12;
    float q0 = q[pt * 3], q1 = q[pt * 3 + 1], q2 = q[pt * 3 + 2];
    float qn = q0 * q0 + q1 * q1 + q2 * q2;
    const float* gb = gt + (size_t)b * M_ * 3;
    const float* gnb = gn + b * M_;
    float best = 1e30f; int bi = 0x7fffffff;
    for (int j = 0; j < 32; j++) {
        int m = sub + 16 * j;
        float dot = q0 * gb[m * 3] + q1 * gb[m * 3 + 1] + q2 * gb[m * 3 + 2];
        float dv = qn + gnb[m] - 2.f * dot;
        if (dv < best || (dv == best && m < bi)) { best = dv; bi = m; }
    }
    for (int off = 8; off; off >>= 1) {
        float ov = __shfl_xor(best, off);
        int oi = __shfl_xor(bi, off);
        if (ov < best || (ov == best && oi < bi)) { best = ov; bi = oi; }
    }
    if (sub == 0) nearest[pt] = clampi(bi, M_);
}

// ---------------------------------------------------------------- nearest D=64 v4: q staged in LDS, 8-row chunks
DEV void nearest64_body_v4(int blk, const float* __restrict__ q,
                           const float* __restrict__ gT, const float* __restrict__ gn,
                           int* __restrict__ nearest,
                           float (*__restrict__ lg)[512], float (*__restrict__ ql)[64]) {
    int lane = threadIdx.x & 63;
    int tid = threadIdx.x;
    int w = __builtin_amdgcn_readfirstlane(threadIdx.x >> 6);
    int pt0 = blk * 16 + w * 4;
    int b = pt0 >> 12;
    const float* gTb = gT + (size_t)b * 64 * M_;
    {
        const float4* q4 = (const float4*)(q + (size_t)(blk * 16) * 64);
        ((float4*)ql)[tid] = q4[tid];
    }
    float qn[4] = {0.f, 0.f, 0.f, 0.f};
    float d[4][8] = {};
#pragma clang loop unroll(disable)
    for (int ch = 0; ch < 8; ch++) {
        __syncthreads();
        {
            const float4* src = (const float4*)(gTb + (size_t)ch * 8 * M_);
            float4* dst = (float4*)lg;
#pragma unroll
            for (int i = 0; i < 4; i++) {
                int idx = i * 256 + tid;
                dst[idx] = src[idx];
            }
        }
        __syncthreads();
#pragma unroll
        for (int j = 0; j < 8; j++) {
            float4 g0 = *(const float4*)&lg[j][4 * lane];
            float4 g1 = *(const float4*)&lg[j][256 + 4 * lane];
#pragma unroll
            for (int p = 0; p < 4; p++) {
                float qc = ql[w * 4 + p][ch * 8 + j];
                qn[p] = fmaf(qc, qc, qn[p]);
                d[p][0] = fmaf(qc, g0.x, d[p][0]); d[p][1] = fmaf(qc, g0.y, d[p][1]);
                d[p][2] = fmaf(qc, g0.z, d[p][2]); d[p][3] = fmaf(qc, g0.w, d[p][3]);
                d[p][4] = fmaf(qc, g1.x, d[p][4]); d[p][5] = fmaf(qc, g1.y, d[p][5]);
                d[p][6] = fmaf(qc, g1.z, d[p][6]); d[p][7] = fmaf(qc, g1.w, d[p][7]);
            }
        }
    }
    const float* gnb = gn + b * M_;
    float4 n0 = *(const float4*)(gnb + 4 * lane);
    float4 n1 = *(const float4*)(gnb + 256 + 4 * lane);
    float nn[8] = {n0.x, n0.y, n0.z, n0.w, n1.x, n1.y, n1.z, n1.w};
#pragma clang loop unroll(disable)
    for (int p = 0; p < 4; p++) {
        float best = 1e30f; int bi = 0;
#pragma unroll
        for (int i = 0; i < 8; i++) {
            int m = (i < 4) ? (4 * lane + i) : (256 + 4 * lane + i - 4);
            float dv = qn[p] + nn[i] - 2.f * d[p][i];
            if (dv < best || (dv == best && m < bi)) { best = dv; bi = m; }
        }
        for (int off = 32; off; off >>= 1) {
            float ov = __shfl_xor(best, off);
            int oi = __shfl_xor(bi, off);
            if (ov < best || (ov == best && oi < bi)) { best = ov; bi = oi; }
        }
        if (lane == 0) nearest[pt0 + p] = clampi(bi, M_);
    }
}

// ---------------------------------------------------------------- exact top-50 via radix-select
DEV void select50(const float dd[8], const int mreg[8], int lane,
                  int* __restrict__ rowp, int* __restrict__ idxrow) {
    u64 key[8];
#pragma unroll
    for (int i = 0; i < 8; i++) {
        unsigned u = __float_as_uint(dd[i]);
        if (u == 0x80000000u) u = 0u;                     // -0.0 -> +0.0
        u = (u & 0x80000000u) ? ~u : (u | 0x80000000u);   // order-preserving map
        key[i] = ((u64)u << 9) | (u64)(unsigned)mreg[i];
    }
    u64 kmin = key[0];
#pragma unroll
    for (int i = 1; i < 8; i++) kmin = key[i] < kmin ? key[i] : kmin;
    for (int off = 32; off; off >>= 1) {
        u64 o = __shfl_xor(kmin, off);
        kmin = o < kmin ? o : kmin;
    }
    u64 res = 0;
#pragma clang loop unroll(disable)
    for (int bit = 40; bit >= 0; --bit) {
        u64 t = res | ((u64)1 << bit);
        int c = 0;
#pragma unroll
        for (int i = 0; i < 8; i++) c += (key[i] < t) ? 1 : 0;
        u64 b0 = __ballot(c & 1), b1 = __ballot(c & 2), b2 = __ballot(c & 4), b3 = __ballot(c & 8);
        int tot = __popcll(b0) + 2 * __popcll(b1) + 4 * __popcll(b2) + 8 * __popcll(b3);
        if (tot <= K_ - 1) res = t;
    }
    int lc = 0, loc[8];
    bool sel[8];
#pragma unroll
    for (int i = 0; i < 8; i++) {
        sel[i] = (key[i] <= res) && (key[i] != kmin);
        loc[i] = lc;
        lc += sel[i] ? 1 : 0;
    }
    u64 lmask = ((u64)1 << lane) - 1;
    u64 c0 = __ballot(lc & 1), c1 = __ballot(lc & 2), c2 = __ballot(lc & 4), c3 = __ballot(lc & 8);
    int pre = __popcll(c0 & lmask) + 2 * __popcll(c1 & lmask)
            + 4 * __popcll(c2 & lmask) + 8 * __popcll(c3 & lmask);
#pragma unroll
    for (int i = 0; i < 8; i++) {
        if (key[i] == kmin) { rowp[0] = mreg[i]; idxrow[0] = mreg[i]; }
        if (sel[i]) { int p = 1 + pre + loc[i]; rowp[p] = mreg[i]; idxrow[p] = mreg[i]; }
    }
}

// ---------------------------------------------------------------- grid KNN D=3 (unstaged distance) + radix select
DEV void nbr3_body(int blk, const float* __restrict__ g, const float* __restrict__ gT,
                   const float* __restrict__ gn, const float* __restrict__ Pg,
                   int* __restrict__ nbr, float* __restrict__ T1, float* __restrict__ T2,
                   float* __restrict__ Mn, float* __restrict__ Mx,
                   int (*__restrict__ idxb)[64]) {
    int lane = threadIdx.x & 63, w = threadIdx.x >> 6;
    int row = blk * 4 + w;
    int b = row >> 9;
    const float* grow = g + (size_t)row * 3;
    float qn = gn[row];
    const float* gTb = gT + (size_t)b * 3 * M_;
    const float* gnb = gn + b * M_;
    float d[8] = {0.f, 0.f, 0.f, 0.f, 0.f, 0.f, 0.f, 0.f};
    {
        float qs[3];
#pragma unroll
        for (int c = 0; c < 3; c++) qs[c] = grow[c];
#pragma unroll
        for (int c = 0; c < 3; c++) {
            float qc = qs[c];
            float4 g0 = *(const float4*)(gTb + c * M_ + 4 * lane);
            float4 g1 = *(const float4*)(gTb + c * M_ + 256 + 4 * lane);
            d[0] = fmaf(qc, g0.x, d[0]); d[1] = fmaf(qc, g0.y, d[1]);
            d[2] = fmaf(qc, g0.z, d[2]); d[3] = fmaf(qc, g0.w, d[3]);
            d[4] = fmaf(qc, g1.x, d[4]); d[5] = fmaf(qc, g1.y, d[5]);
            d[6] = fmaf(qc, g1.z, d[6]); d[7] = fmaf(qc, g1.w, d[7]);
        }
    }
    float4 n0 = *(const float4*)(gnb + 4 * lane);
    float4 n1 = *(const float4*)(gnb + 256 + 4 * lane);
    float dd[8];
    dd[0] = qn + n0.x - 2.f * d[0]; dd[1] = qn + n0.y - 2.f * d[1];
    dd[2] = qn + n0.z - 2.f * d[2]; dd[3] = qn + n0.w - 2.f * d[3];
    dd[4] = qn + n1.x - 2.f * d[4]; dd[5] = qn + n1.y - 2.f * d[5];
    dd[6] = qn + n1.z - 2.f * d[6]; dd[7] = qn + n1.w - 2.f * d[7];
    int mreg[8];
#pragma unroll
    for (int i = 0; i < 8; i++) mreg[i] = (i < 4) ? (4 * lane + i) : (256 + 4 * lane + i - 4);
    select50(dd, mreg, lane, nbr + (size_t)row * K_, idxb[w]);
    int myIdx = idxb[w][lane];
    const float* Pgb = Pg + (size_t)b * M_ * 64;
    float t1 = 0.f, t2 = 0.f, mn = 1e30f, mx = -1e30f;
#pragma unroll 7
    for (int k = 1; k < K_; k++) {
        int idx = clampi(__shfl(myIdx, k), M_);
        float v = Pgb[(size_t)idx * 64 + lane];
        t1 += v; t2 = fmaf(v, v, t2);
        mn = fminf(mn, v); mx = fmaxf(mx, v);
    }
    size_t o = (size_t)row * 64 + lane;
    T1[o] = t1; T2[o] = t2; Mn[o] = mn; Mx[o] = mx;
}

// ---------------------------------------------------------------- grid KNN D=64 (staged distance) + radix select
DEV void nbr64_body(int blk, const float* __restrict__ g, const float* __restrict__ gT,
                    const float* __restrict__ gn, const float* __restrict__ Pg,
                    int* __restrict__ nbr, float* __restrict__ T1, float* __restrict__ T2,
                    float* __restrict__ Mn, float* __restrict__ Mx,
                    float (*__restrict__ lg)[512], float (*__restrict__ ql)[64],
                    int (*__restrict__ idxb)[64]) {
    int lane = threadIdx.x & 63, w = threadIdx.x >> 6;
    int tid = threadIdx.x;
    int row = blk * 4 + w;
    int b = row >> 9;
    float qn = gn[row];
    const float* gTb = gT + (size_t)b * 64 * M_;
    const float* gnb = gn + b * M_;
    if (tid < 64) {
        const float4* q4 = (const float4*)(g + (size_t)(blk * 4) * 64);
        ((float4*)ql)[tid] = q4[tid];
    }
    float d[8] = {0.f, 0.f, 0.f, 0.f, 0.f, 0.f, 0.f, 0.f};
#pragma clang loop unroll(disable)
    for (int ch = 0; ch < 8; ch++) {
        __syncthreads();
        {
            const float4* src = (const float4*)(gTb + (size_t)ch * 8 * M_);
            float4* dst = (float4*)lg;
#pragma unroll
            for (int i = 0; i < 4; i++) {
                int idx = i * 256 + tid;
                dst[idx] = src[idx];
            }
        }
        __syncthreads();
#pragma unroll
        for (int j = 0; j < 8; j++) {
            float qc = ql[w][ch * 8 + j];   // uniform ds_read (broadcast)
            float4 g0 = *(const float4*)&lg[j][4 * lane];
            float4 g1 = *(const float4*)&lg[j][256 + 4 * lane];
            d[0] = fmaf(qc, g0.x, d[0]); d[1] = fmaf(qc, g0.y, d[1]);
            d[2] = fmaf(qc, g0.z, d[2]); d[3] = fmaf(qc, g0.w, d[3]);
            d[4] = fmaf(qc, g1.x, d[4]); d[5] = fmaf(qc, g1.y, d[5]);
            d[6] = fmaf(qc, g1.z, d[6]); d[7] = fmaf(qc, g1.w, d[7]);
        }
    }
    float4 n0 = *(const float4*)(gnb + 4 * lane);
    float4 n1 = *(const float4*)(gnb + 256 + 4 * lane);
    float dd[8];
    dd[0] = qn + n0.x - 2.f * d[0]; dd[1] = qn + n0.y - 2.f * d[1];
    dd[2] = qn + n0.z - 2.f * d[2]; dd[3] = qn + n0.w - 2.f * d[3];
    dd[4] = qn + n1.x - 2.f * d[4]; dd[5] = qn + n1.y - 2.f * d[5];
    dd[6] = qn + n1.z - 2.f * d[6]; dd[7] = qn + n1.w - 2.f * d[7];
    int mreg[8];
#pragma unroll
    for (int i = 0; i < 8; i++) mreg[i] = (i < 4) ? (4 * lane + i) : (256 + 4 * lane + i - 4);
    select50(dd, mreg, lane, nbr + (size_t)row * K_, idxb[w]);
    int myIdx = idxb[w][lane];
    const float* Pgb = Pg + (size_t)b * M_ * 64;
    float t1 = 0.f, t2 = 0.f, mn = 1e30f, mx = -1e30f;
#pragma unroll 7
    for (int k = 1; k < K_; k++) {
        int idx = clampi(__shfl(myIdx, k), M_);
        float v = Pgb[(size_t)idx * 64 + lane];
        t1 += v; t2 = fmaf(v, v, t2);
        mn = fminf(mn, v); mx = fmaxf(mx, v);
    }
    size_t o = (size_t)row * 64 + lane;
    T1[o] = t1; T2[o] = t2; Mn[o] = mn; Mx[o] = mx;
}

// ---------------------------------------------------------------- fused KNN launches
__global__ __launch_bounds__(256) void k_knn3(
    const float* __restrict__ q, const float* __restrict__ gt, const float* __restrict__ gT3,
    const float* __restrict__ gn, const float* __restrict__ Pg,
    int* __restrict__ nearest, int* __restrict__ nbr, float* __restrict__ T1,
    float* __restrict__ T2, float* __restrict__ Mn, float* __restrict__ Mx) {
    __shared__ int idxb[4][64];
    if (blockIdx.x < BN / 16) nearest3_body(blockIdx.x, q, gt, gn, nearest);
    else nbr3_body(blockIdx.x - BN / 16, gt, gT3, gn, Pg, nbr, T1, T2, Mn, Mx, idxb);
}
__global__ __launch_bounds__(256) void k_knn64(
    const float* __restrict__ q, const float* __restrict__ xgt, const float* __restrict__ gT,
    const float* __restrict__ gn, const float* __restrict__ Pg,
    int* __restrict__ nearest, int* __restrict__ nbr, float* __restrict__ T1,
    float* __restrict__ T2, float* __restrict__ Mn, float* __restrict__ Mx) {
    __shared__ float lg[8][512];   // 16 KB staging panel
    __shared__ float ql[16][64];   // 4 KB q rows
    __shared__ int idxb[4][64];    // 1 KB selected-index rows
    if (blockIdx.x < BN / 16) nearest64_body_v4(blockIdx.x, q, gT, gn, nearest, lg, ql);
    else nbr64_body(blockIdx.x - BN / 16, xgt, gT, gn, Pg, nbr, T1, T2, Mn, Mx, lg, ql, idxb);
}

// ---------------------------------------------------------------- deterministic block stats store
#define STATS_STORE_64(s1v, s2v, partial)                                         \
    {                                                                             \
        __shared__ float r1_[256], r2_[256];                                      \
        r1_[threadIdx.x] = (s1v); r2_[threadIdx.x] = (s2v);                       \
        __syncthreads();                                                          \
        if (threadIdx.x < 64) {                                                   \
            int t_ = threadIdx.x;                                                 \
            float a1_ = r1_[t_] + r1_[t_ + 64] + r1_[t_ + 128] + r1_[t_ + 192];   \
            float a2_ = r2_[t_] + r2_[t_ + 64] + r2_[t_ + 128] + r2_[t_ + 192];   \
            float* sp_ = (partial) + (size_t)blockIdx.x * 128;                    \
            sp_[t_] = a1_; sp_[64 + t_] = a2_;                                    \
        }                                                                         \
    }

// ---------------------------------------------------------------- Pg for stage A (D=3)
__global__ __launch_bounds__(256) void k_pgrid3(const float* __restrict__ g,
                                                const float* __restrict__ W1,
                                                float* __restrict__ Pg) {
    int lane = threadIdx.x & 63;
    int row = blockIdx.x * 4 + __builtin_amdgcn_readfirstlane(threadIdx.x >> 6);
    float c0 = g[row * 3], c1 = g[row * 3 + 1], c2 = g[row * 3 + 2];
    const float* wr = W1 + lane * 6;
    Pg[(size_t)row * 64 + lane] = fmaf(wr[0], c0, fmaf(wr[1], c1, wr[2] * c2));
}

// ---------------------------------------------------------------- fused grid prep (stages B/C)
__global__ __launch_bounds__(256) void k_gridprep(
    const float* __restrict__ xsrc, const int* __restrict__ FPS,
    const float* __restrict__ Wt, float* __restrict__ xgt, float* __restrict__ gT,
    float* __restrict__ gn, float* __restrict__ Pg) {
    int lane = threadIdx.x & 63, w = threadIdx.x >> 6;
    int row = blockIdx.x * 4 + w;
    int b = row >> 9, m = row & 511;
    int src = b * N_ + clampi(FPS[row], N_);
    float ge = xsrc[(size_t)src * 64 + lane];
    xgt[(size_t)row * 64 + lane] = ge;
    gT[((size_t)b * 64 + lane) * M_ + m] = ge;
    float s = 0.f, acc = 0.f;
#pragma unroll
    for (int c = 0; c < 64; c++) {
        float vc = __shfl(ge, c);
        s = fmaf(vc, vc, s);
        acc = fmaf(Wt[c * 64 + lane], vc, acc);
    }
    Pg[(size_t)row * 64 + lane] = acc;
    if (lane == 0) gn[row] = s;
}

// ---------------------------------------------------------------- fused prep + BN stats of y1
template <int D>
__global__ __launch_bounds__(256) void k_prep_stats(
    const float* __restrict__ q, const float* __restrict__ W1,
    const int* __restrict__ nearest, const float* __restrict__ T1,
    const float* __restrict__ T2, float* __restrict__ D0, float* __restrict__ S0,
    float* __restrict__ partial) {
    int lane = threadIdx.x & 63;
    int pt = blockIdx.x * 4 + __builtin_amdgcn_readfirstlane(threadIdx.x >> 6);
    int b = pt >> 12;
    float pa, pb;
    if constexpr (D == 3) {
        float c0 = q[pt * 3], c1 = q[pt * 3 + 1], c2 = q[pt * 3 + 2];
        const float* wr = W1 + lane * 6;
        pa = fmaf(wr[0], c0, fmaf(wr[1], c1, wr[2] * c2));
        pb = fmaf(wr[3], c0, fmaf(wr[4], c1, wr[5] * c2));
    } else {
        float ge = q[(size_t)pt * 64 + lane];
        pa = 0.f; pb = 0.f;
#pragma unroll
        for (int c = 0; c < 64; c++) {
            float sh = __shfl(ge, c);
            pa = fmaf(W1[c * 64 + lane], sh, pa);
            pb = fmaf(W1[(64 + c) * 64 + lane], sh, pb);
        }
    }
    float d0 = pb - pa, s0 = pb;
    size_t t = (size_t)pt * 64 + lane;
    D0[t] = d0;
    S0[t] = s0;
    size_t nr = ((size_t)b * M_ + clampi(nearest[pt], M_)) * 64 + lane;
    float t1 = T1[nr], t2 = T2[nr];
    float s1 = s0 + fmaf(49.f, d0, t1);
    float s2 = fmaf(s0, s0, fmaf(49.f * d0, d0, fmaf(2.f * d0, t1, t2)));
    STATS_STORE_64(s1, s2, partial)
}

// ---------------------------------------------------------------- stage-C output: bn+lrelu(max) exact
__global__ void k_apply0(const float* __restrict__ D0, const float* __restrict__ S0,
                         const int* __restrict__ nearest, const float* __restrict__ Mn,
                         const float* __restrict__ Mx, const float* __restrict__ prm,
                         float* __restrict__ xout) {
    int t = blockIdx.x * 256 + threadIdx.x;
    int pt = t >> 6, o = t & 63;
    int b = pt >> 12;
    size_t nr = ((size_t)b * M_ + clampi(nearest[pt], M_)) * 64 + o;
    float d0 = D0[t], s0 = S0[t];
    float a = prm[o], sh = prm[64 + o];
    float v = a > 0.f ? fmaxf(s0, d0 + Mx[nr]) : fminf(s0, d0 + Mn[nr]);
    xout[t] = lrelu(fmaf(a, v, sh));
}

// ---------------------------------------------------------------- pass1 via MFMA (3-term bf16 split, coalesced gather,
// ubuf folded in: u = fmaf(a, Pg, sh) computed inline -- the exact single
// fmaf k_ubuf performed, bit-identical, saves 2 launches + a global pass)
__global__ __launch_bounds__(256) void k_pass1_mfma(
    const float* __restrict__ Pg, const float* __restrict__ D0,
    const float* __restrict__ S0, const int* __restrict__ nearest,
    const int* __restrict__ nbr, const float* __restrict__ prm1,
    const u16* __restrict__ wf, float* __restrict__ partial,
    float* __restrict__ mn_out, float* __restrict__ mx_out) {
    __shared__ u16 Zs[2][2][4096];   // 32 KB; first 1KB reused as ls1/ls2 post-MFMA
    __shared__ int idxl[2][64];
    float* ls1 = (float*)&Zs[0][0][0];
    float* ls2 = ls1 + 128;
    int l = threadIdx.x & 63;
    int w = threadIdx.x >> 6;
    int wp = w >> 1, nh = w & 1;     // wave's point, wave's o-half
    bf8v whi[2][2], wlo[2][2];
#pragma unroll
    for (int nt = 0; nt < 2; nt++)
#pragma unroll
        for (int s = 0; s < 2; s++) {
            int fi = (((nh * 2 + nt) * 2 + s) * 64 + l) * 8;
            whi[nt][s] = *(const bf8v*)(wf + fi);
            wlo[nt][s] = *(const bf8v*)(wf + 4096 + fi);
        }
    // ---- neighbor-id gather: threads 0..127, one id each ----
    if (threadIdx.x < 128) {
        int p2 = threadIdx.x >> 6, k = threadIdx.x & 63;
        int pt2 = blockIdx.x * 2 + p2, b2 = pt2 >> 12;
        int nr = clampi(nearest[pt2], M_);
        idxl[p2][k] = (k >= 1 && k < K_)
                          ? clampi(nbr[((size_t)b2 * M_ + nr) * K_ + k], M_) : 0;
    }
    __syncthreads();
    // ---- Z build: per point, group g=tt>>4 owns row k=s*8+g; lane j=tt&15 owns cols j*4.. ----
    {
        int tt = threadIdx.x & 127;
        int p = threadIdx.x >> 7;
        int pt = blockIdx.x * 2 + p, b = pt >> 12;
        int g = tt >> 4, j = tt & 15;
        char* zh = (char*)&Zs[p][0][0];
        char* zl = (char*)&Zs[p][1][0];
        float4 a = ((const float4*)prm1)[j];
        float4 sh4 = ((const float4*)(prm1 + 64))[j];
        float4 dv = ((const float4*)(D0 + (size_t)pt * 64))[j];
        const float* Pgb = Pg + (size_t)b * M_ * 64;
#pragma unroll
        for (int s = 0; s < 8; s++) {
            int k = s * 8 + g;
            float4 u, d = dv;
            if (k == 0) {   // center row: fold bn into u, d=0 (bit-exact old path)
                float4 s0 = ((const float4*)(S0 + (size_t)pt * 64))[j];
                u.x = fmaf(a.x, s0.x, sh4.x); u.y = fmaf(a.y, s0.y, sh4.y);
                u.z = fmaf(a.z, s0.z, sh4.z); u.w = fmaf(a.w, s0.w, sh4.w);
                d.x = 0.f; d.y = 0.f; d.z = 0.f; d.w = 0.f;
            } else {
                int idx = idxl[p][k];
                float4 pg = ((const float4*)(Pgb + (size_t)idx * 64))[j];
                u.x = fmaf(a.x, pg.x, sh4.x); u.y = fmaf(a.y, pg.y, sh4.y);
                u.z = fmaf(a.z, pg.z, sh4.z); u.w = fmaf(a.w, pg.w, sh4.w);
            }
            float z0 = lrelu(fmaf(a.x, d.x, u.x));
            float z1 = lrelu(fmaf(a.y, d.y, u.y));
            float z2 = lrelu(fmaf(a.z, d.z, u.z));
            float z3 = lrelu(fmaf(a.w, d.w, u.w));
            if (k >= K_) { z0 = 0.f; z1 = 0.f; z2 = 0.f; z3 = 0.f; }
            unsigned h01 = cvtpk(z0, z1), h23 = cvtpk(z2, z3);
            float r0 = z0 - __uint_as_float(h01 << 16);
            float r1 = z1 - __uint_as_float(h01 & 0xFFFF0000u);
            float r2 = z2 - __uint_as_float(h23 << 16);
            float r3 = z3 - __uint_as_float(h23 & 0xFFFF0000u);
            unsigned l01 = cvtpk(r0, r1), l23 = cvtpk(r2, r3);
            int ad = k * 128 + ((j * 8) ^ ((k & 7) << 4));   // same swizzled layout
            *(uint2*)(zh + ad) = make_uint2(h01, h23);
            *(uint2*)(zl + ad) = make_uint2(l01, l23);
        }
    }
    __syncthreads();
    // ---- MFMA: wave computes Y[64k x 32o] for its point ----
    int pt = blockIdx.x * 2 + wp;
    const char* zh = (const char*)&Zs[wp][0][0];
    const char* zl = (const char*)&Zs[wp][1][0];
    f4v acc[4][2] = {};
#pragma unroll
    for (int s = 0; s < 2; s++) {
        bf8v ah[4], al[4];
#pragma unroll
        for (int m = 0; m < 4; m++) {
            int row = m * 16 + (l & 15);
            int ad = row * 128 + (((s * 64) + ((l >> 4) * 16)) ^ ((row & 7) << 4));
            ah[m] = *(const bf8v*)(zh + ad);
            al[m] = *(const bf8v*)(zl + ad);
        }
#pragma unroll
        for (int m = 0; m < 4; m++)
#pragma unroll
            for (int nt = 0; nt < 2; nt++) {
                acc[m][nt] = __builtin_amdgcn_mfma_f32_16x16x32_bf16(ah[m], whi[nt][s], acc[m][nt], 0, 0, 0);
                acc[m][nt] = __builtin_amdgcn_mfma_f32_16x16x32_bf16(al[m], whi[nt][s], acc[m][nt], 0, 0, 0);
                acc[m][nt] = __builtin_amdgcn_mfma_f32_16x16x32_bf16(ah[m], wlo[nt][s], acc[m][nt], 0, 0, 0);
            }
    }
    __syncthreads();   // Zs reads complete; ls1/ls2 alias region now safe to write
    int rg = (l >> 4) * 4;
#pragma unroll
    for (int nt = 0; nt < 2; nt++) {
        float s1 = 0.f, s2 = 0.f, mn = 1e30f, mx = -1e30f;
#pragma unroll
        for (int m = 0; m < 4; m++)
#pragma unroll
            for (int i = 0; i < 4; i++) {
                int kk = m * 16 + rg + i;
                float v = acc[m][nt][i];
                if (kk < K_) { s1 += v; s2 = fmaf(v, v, s2); mn = fminf(mn, v); mx = fmaxf(mx, v); }
            }
        for (int off = 16; off <= 32; off <<= 1) {
            s1 += __shfl_xor(s1, off); s2 += __shfl_xor(s2, off);
            mn = fminf(mn, __shfl_xor(mn, off)); mx = fmaxf(mx, __shfl_xor(mx, off));
        }
        if (l < 16) {
            int o = nh * 32 + nt * 16 + l;
            mn_out[(size_t)pt * 64 + o] = mn;
            mx_out[(size_t)pt * 64 + o] = mx;
            ls1[wp * 64 + o] = s1;
            ls2[wp * 64 + o] = s2;
        }
    }
    __syncthreads();
    if (threadIdx.x < 64) {
        int t = threadIdx.x;
        float* sp = partial + (size_t)blockIdx.x * 128;
        sp[t] = ls1[t] + ls1[64 + t];
        sp[64 + t] = ls2[t] + ls2[64 + t];
    }
}

// ---------------------------------------------------------------- apply bn+lrelu to min/max (exact)
__global__ void k_apply(const float* __restrict__ mn, const float* __restrict__ mx,
                        const float* __restrict__ prm, float* __restrict__ xout) {
    int t = blockIdx.x * 256 + threadIdx.x;
    int o = t & 63;
    float a = prm[o], sh = prm[64 + o];
    float v = a > 0.f ? mx[t] : mn[t];
    xout[t] = lrelu(fmaf(a, v, sh));
}

// ---------------------------------------------------------------- fused reduce+finalize (32 blocks)
template <int NP, int O>
__global__ __launch_bounds__(256) void k_redfin(
    const float* __restrict__ partial, double* __restrict__ red,
    int* __restrict__ counter, int C,
    const float* __restrict__ g, const float* __restrict__ bt,
    float* __restrict__ prm) {
    constexpr int VALS = 2 * O;
    constexpr int G = NP / 32;
    int b = blockIdx.x;   // 32 blocks
    for (int v = threadIdx.x; v < VALS; v += 256) {
        const float* p = partial + (size_t)b * G * VALS + v;
        double s = 0.0;
        for (int k = 0; k < G; k++) s += p[(size_t)k * VALS];
        red[(size_t)b * VALS + v] = s;
    }
    __threadfence();
    __syncthreads();
    __shared__ bool isLast;
    if (threadIdx.x == 0) isLast = (atomicAdd(counter, 1) == 31);
    __syncthreads();
    if (!isLast) return;
    __threadfence();
    for (int o = threadIdx.x; o < O; o += 256) {
        double s1 = 0.0, s2 = 0.0;
#pragma unroll
        for (int k = 0; k < 32; k++) {
            s1 += red[(size_t)k * VALS + o];
            s2 += red[(size_t)k * VALS + O + o];
        }
        double m = s1 / C, var = s2 / C - m * m;
        if (var < 0) var = 0;
        float sc = g[o] / sqrtf((float)var + EPS_);
        prm[o] = sc;
        prm[O + o] = bt[o] - (float)m * sc;
    }
}

// ---------------------------------------------------------------- W6 conv (192->512), Wt-coalesced, 4-row tiles
__global__ __launch_bounds__(256) void k_conv_w6(
    const float* __restrict__ x1gt, const float* __restrict__ x2gt,
    const float* __restrict__ x3t, const int* __restrict__ FPS,
    const float* __restrict__ W6t, float* __restrict__ y6, float* __restrict__ partial) {
    __shared__ float vl[4][192];
    int b = blockIdx.x / 128;
    int m0 = (blockIdx.x % 128) * 4;
    for (int i = threadIdx.x; i < 4 * 192; i += 256) {
        int mi = i / 192, c = i % 192;
        float v;
        if (c < 128) {
            const float* src = c < 64 ? x1gt : x2gt;
            v = src[((size_t)b * M_ + m0 + mi) * 64 + (c & 63)];
        } else {
            int s = b * N_ + clampi(FPS[b * M_ + m0 + mi], N_);
            v = x3t[(size_t)s * 64 + (c - 128)];
        }
        vl[mi][c] = v;
    }
    __syncthreads();
    float acc0[4] = {0}, acc1[4] = {0};
    int o0 = threadIdx.x, o1 = threadIdx.x + 256;
    for (int c = 0; c < 192; c++) {
        float w0 = W6t[c * 512 + o0];
        float w1 = W6t[c * 512 + o1];
#pragma unroll
        for (int m = 0; m < 4; m++) { float v = vl[m][c]; acc0[m] = fmaf(w0, v, acc0[m]); acc1[m] = fmaf(w1, v, acc1[m]); }
    }
    float s1a = 0, s2a = 0, s1b = 0, s2b = 0;
    for (int m = 0; m < 4; m++) {
        float ya = acc0[m], yb = acc1[m];
        y6[((size_t)b * M_ + m0 + m) * 512 + o0] = ya;
        y6[((size_t)b * M_ + m0 + m) * 512 + o1] = yb;
        s1a += ya; s2a = fmaf(ya, ya, s2a); s1b += yb; s2b = fmaf(yb, yb, s2b);
    }
    float* sp = partial + (size_t)blockIdx.x * 1024;
    sp[o0] = s1a; sp[512 + o0] = s2a;
    sp[o1] = s1b; sp[512 + o1] = s2b;
}

// ---------------------------------------------------------------- bn6+lrelu+max over M (128 blocks)
__global__ void k_maxM(const float* __restrict__ y6, const float* __restrict__ prm,
                       float* __restrict__ xgmax) {
    int blk = blockIdx.x;            // B_*64
    int b = blk >> 6;
    int obase = (blk & 63) << 3;
    int o = obase + (threadIdx.x & 7);
    int mg = threadIdx.x >> 3;       // 32 m-groups
    float a = prm[o], sh = prm[512 + o];
    float mx = -1e30f;
    for (int m = mg; m < M_; m += 32)
        mx = fmaxf(mx, lrelu(fmaf(a, y6[((size_t)b * M_ + m) * 512 + o], sh)));
    __shared__ float red[256];
    red[threadIdx.x] = mx;
    __syncthreads();
    for (int s = 128; s >= 8; s >>= 1) {
        if (threadIdx.x < s) red[threadIdx.x] = fmaxf(red[threadIdx.x], red[threadIdx.x + s]);
        __syncthreads();
    }
    if (threadIdx.x < 8) xgmax[b * 512 + obase + threadIdx.x] = red[threadIdx.x];
}

// ---------------------------------------------------------------- P7: wave per output (fixed xor tree)
__global__ __launch_bounds__(256) void k_p7(const float* __restrict__ xgmax,
                                            const float* __restrict__ W7,
                                            float* __restrict__ p7) {
    int lane = threadIdx.x & 63, w = threadIdx.x >> 6;
    int t = blockIdx.x * 4 + w;     // 0..255
    int b = t >> 7, o = t & 127;
    float acc = 0.f;
#pragma unroll
    for (int j = 0; j < 8; j++) {
        int c = j * 64 + lane;
        acc = fmaf(W7[o * 704 + c], xgmax[b * 512 + c], acc);
    }
    for (int off = 32; off; off >>= 1) acc += __shfl_xor(acc, off);
    if (lane == 0) p7[t] = acc;
}

// ---------------------------------------------------------------- W7 conv (192-col part) via MFMA, 16 items/block
__global__ __launch_bounds__(256) void k_conv_w7m(
    const float* __restrict__ x1t, const float* __restrict__ x2t,
    const float* __restrict__ x3t, const float* __restrict__ p7,
    const u16* __restrict__ wf7, float* __restrict__ y7, float* __restrict__ partial) {
    __shared__ u16 Zh[16][200], Zl[16][200];   // 12.5 KB
    int tid = threadIdx.x;
    int l = tid & 63, w = tid >> 6;
    int item0 = blockIdx.x * 16;
    int b = blockIdx.x >> 8;                    // 512 blocks, 256 per batch
    bf8v wh[2][6], wl[2][6];
#pragma unroll
    for (int nt = 0; nt < 2; nt++)
#pragma unroll
        for (int s = 0; s < 6; s++) {
            int fi = (((2 * w + nt) * 6 + s) * 64 + l) * 8;
            wh[nt][s] = *(const bf8v*)(wf7 + fi);
            wl[nt][s] = *(const bf8v*)(wf7 + 24576 + fi);
        }
    {
        int item = tid >> 4, seg = tid & 15;
        if (seg < 12) {
            const float* sp_;
            size_t base = (size_t)(item0 + item) * 64;
            if (seg < 4) sp_ = x1t + base + seg * 16;
            else if (seg < 8) sp_ = x2t + base + (seg - 4) * 16;
            else sp_ = x3t + base + (seg - 8) * 16;
            float f[16];
#pragma unroll
            for (int i = 0; i < 4; i++) {
                float4 v = ((const float4*)sp_)[i];
                f[4 * i] = v.x; f[4 * i + 1] = v.y; f[4 * i + 2] = v.z; f[4 * i + 3] = v.w;
            }
            unsigned hp[8], lp[8];
#pragma unroll
            for (int e = 0; e < 8; e++) {
                unsigned h = cvtpk(f[2 * e], f[2 * e + 1]);
                float r0 = f[2 * e] - __uint_as_float(h << 16);
                float r1 = f[2 * e + 1] - __uint_as_float(h & 0xFFFF0000u);
                hp[e] = h;
                lp[e] = cvtpk(r0, r1);
            }
            uint4* dh = (uint4*)&Zh[item][seg * 16];
            uint4* dl = (uint4*)&Zl[item][seg * 16];
            dh[0] = make_uint4(hp[0], hp[1], hp[2], hp[3]);
            dh[1] = make_uint4(hp[4], hp[5], hp[6], hp[7]);
            dl[0] = make_uint4(lp[0], lp[1], lp[2], lp[3]);
            dl[1] = make_uint4(lp[4], lp[5], lp[6], lp[7]);
        }
    }
    __syncthreads();
    f4v acc[2] = {};
#pragma unroll
    for (int s = 0; s < 6; s++) {
        int row = l & 15, col = s * 32 + (l >> 4) * 8;
        bf8v ah = *(const bf8v*)&Zh[row][col];
        bf8v al = *(const bf8v*)&Zl[row][col];
#pragma unroll
        for (int nt = 0; nt < 2; nt++) {
            acc[nt] = __builtin_amdgcn_mfma_f32_16x16x32_bf16(ah, wh[nt][s], acc[nt], 0, 0, 0);
            acc[nt] = __builtin_amdgcn_mfma_f32_16x16x32_bf16(al, wh[nt][s], acc[nt], 0, 0, 0);
            acc[nt] = __builtin_amdgcn_mfma_f32_16x16x32_bf16(ah, wl[nt][s], acc[nt], 0, 0, 0);
        }
    }
#pragma unroll
    for (int nt = 0; nt < 2; nt++) {
        int o = (2 * w + nt) * 16 + (l & 15);
        float pv = p7[b * 128 + o];
        float s1 = 0.f, s2 = 0.f;
#pragma unroll
        for (int i = 0; i < 4; i++) {
            int item = (l >> 4) * 4 + i;
            float yv = pv + acc[nt][i];
            y7[(size_t)(item0 + item) * 128 + o] = yv;
            s1 += yv; s2 = fmaf(yv, yv, s2);
        }
        for (int off = 16; off <= 32; off <<= 1) {
            s1 += __shfl_xor(s1, off);
            s2 += __shfl_xor(s2, off);
        }
        if (l < 16) {
            float* sp = partial + (size_t)blockIdx.x * 256;
            sp[o] = s1;
            sp[128 + o] = s2;
        }
    }
}

// ---------------------------------------------------------------- W8 conv (128->64), Wt-coalesced
__global__ __launch_bounds__(256) void k_conv_w8(
    const float* __restrict__ y7, const float* __restrict__ prm7,
    const float* __restrict__ W8t, float* __restrict__ y8, float* __restrict__ partial) {
    int lane = threadIdx.x & 63;
    int item = blockIdx.x * 4 + (threadIdx.x >> 6);
    float W0[64], W1r[64];
#pragma unroll
    for (int c = 0; c < 64; c++) {
        W0[c] = W8t[c * 64 + lane];
        W1r[c] = W8t[(64 + c) * 64 + lane];
    }
    float a0 = prm7[lane], sh0 = prm7[128 + lane];
    float a1 = prm7[64 + lane], sh1 = prm7[128 + 64 + lane];
    float z0 = lrelu(fmaf(a0, y7[(size_t)item * 128 + lane], sh0));
    float z1 = lrelu(fmaf(a1, y7[(size_t)item * 128 + 64 + lane], sh1));
    float acc = 0.f;
#pragma unroll
    for (int c = 0; c < 64; c++) {
        acc = fmaf(W0[c], __shfl(z0, c), acc);
        acc = fmaf(W1r[c], __shfl(z1, c), acc);
    }
    y8[(size_t)item * 64 + lane] = acc;
    STATS_STORE_64(acc, acc * acc, partial)
}

// ---------------------------------------------------------------- final: bn8+lrelu, W9t -> out
__global__ __launch_bounds__(256) void k_final(
    const float* __restrict__ y8, const float* __restrict__ prm8,
    const float* __restrict__ W9t, void* __restrict__ out, const int* __restrict__ flag) {
    __shared__ float zl[2][64];
    int item0 = blockIdx.x * 2;
    if (threadIdx.x < 128) {
        int it = threadIdx.x >> 6, c = threadIdx.x & 63;
        float z = fmaf(prm8[c], y8[(size_t)(item0 + it) * 64 + c], prm8[64 + c]);
        zl[it][c] = lrelu(z);
    }
    __syncthreads();
    int it = threadIdx.x >> 7, o = threadIdx.x & 127;
    float acc = 0.f;
#pragma unroll
    for (int c = 0; c < 64; c++) acc = fmaf(W9t[c * 128 + o], zl[it][c], acc);
    size_t oi = (size_t)(item0 + it) * 128 + o;
    if (*flag) ((bf16*)out)[oi] = __float2bfloat16(acc);
    else ((float*)out)[oi] = acc;
}

// ---------------------------------------------------------------- host
extern "C" void kernel_launch(void* const* d_in, const int* in_sizes, int n_in,
                              void* d_out, int out_size, void* d_ws, size_t ws_size,
                              hipStream_t stream) {
    (void)in_sizes; (void)n_in; (void)out_size; (void)ws_size;
    const void* x = d_in[0];
    const void* xgrid = d_in[1];
    const int* FPS = (const int*)d_in[2];

    char* ws = (char*)d_ws;
    size_t off = 0;
    auto alloc = [&](size_t bytes) -> char* {
        char* p = ws + off;
        off = (off + bytes + 255) & ~(size_t)255;
        return p;
    };
    int* flag       = (int*)alloc(256);
    int* counters   = (int*)alloc(256);
    float* partials = (float*)alloc((size_t)4096 * 128 * sizeof(float));   // 2 MB (pass1 grid = 4096)
    double* redbuf  = (double*)alloc(32 * 1024 * sizeof(double));  // 256 KB
    float* prm      = (float*)alloc(8 * 1024 * sizeof(float));
    static const int wsz[9] = {384, 4096, 8192, 4096, 8192, 98304, 90112, 8192, 8192};
    static const int dims[8] = {64, 64, 64, 64, 64, 512, 128, 64};
    float* cW[9];
    for (int i = 0; i < 9; i++) cW[i] = (float*)alloc((size_t)wsz[i] * 4);
    float* cG[8];
    float* cB[8];
    for (int j = 0; j < 8; j++) {
        cG[j] = (float*)alloc((size_t)dims[j] * 4);
        cB[j] = (float*)alloc((size_t)dims[j] * 4);
    }
    float* W6t  = (float*)alloc((size_t)512 * 192 * 4);
    float* W7vt = (float*)alloc((size_t)128 * 192 * 4);
    float* W8t  = (float*)alloc((size_t)64 * 128 * 4);
    float* W9t  = (float*)alloc((size_t)128 * 64 * 4);
    float* W3t  = (float*)alloc((size_t)64 * 128 * 4);
    float* W5t  = (float*)alloc((size_t)64 * 128 * 4);
    u16* wf2    = (u16*)alloc((size_t)8192 * 2);    // W2 MFMA frags hi+lo
    u16* wf4    = (u16*)alloc((size_t)8192 * 2);    // W4 MFMA frags hi+lo
    u16* wf7    = (u16*)alloc((size_t)49152 * 2);   // W7 MFMA frags hi+lo
    float* xt    = (float*)alloc((size_t)BN * 3 * 4);
    float* gt    = (float*)alloc((size_t)BM * 3 * 4);
    float* gT3   = (float*)alloc((size_t)B_ * 3 * M_ * 4);
    float* gn    = (float*)alloc((size_t)BM * 4);
    int* nearest = (int*)alloc((size_t)BN * 4);
    int* nbr     = (int*)alloc((size_t)BM * K_ * 4);
    float* Pg    = (float*)alloc((size_t)BM * 64 * 4);
    float* x1t   = (float*)alloc((size_t)BN * 64 * 4);
    float* x2t   = (float*)alloc((size_t)BN * 64 * 4);
    float* x3t   = (float*)alloc((size_t)BN * 64 * 4);
    float* x1gt  = (float*)alloc((size_t)BM * 64 * 4);
    float* x2gt  = (float*)alloc((size_t)BM * 64 * 4);
    float* gT64  = (float*)alloc((size_t)B_ * 64 * M_ * 4);
    float* y6    = (float*)alloc((size_t)BM * 512 * 4);
    float* xgmax = (float*)alloc((size_t)B_ * 512 * 4);
    float* p7    = (float*)alloc((size_t)B_ * 128 * 4);
    float* y7    = (float*)alloc((size_t)BN * 128 * 4);
    float* y8    = (float*)alloc((size_t)BN * 64 * 4);
    // Aliases (lifetimes verified; same layout as passing rounds):
    float* D0b = y7;
    float* S0b = y7 + (size_t)BN * 64;
    float* mnb = y8;
    float* mxb = y6;
    float* T1b = y6;
    float* T2b = y6 + (size_t)BM * 64;
    float* Mnb = y6 + (size_t)2 * BM * 64;
    float* Mxb = y6 + (size_t)3 * BM * 64;

    hipMemsetAsync(counters, 0, 8 * sizeof(int), stream);
    k_detect<<<1, 256, 0, stream>>>((const unsigned short*)x, flag);

    SetupArgs sa;
    for (int i = 0; i < 9; i++) sa.d[i] = {d_in[3 + i], cW[i], wsz[i]};
    for (int j = 0; j < 8; j++) {
        sa.d[9 + 2 * j]     = {d_in[12 + 2 * j], cG[j], dims[j]};
        sa.d[9 + 2 * j + 1] = {d_in[13 + 2 * j], cB[j], dims[j]};
    }
    sa.t[0] = {d_in[8],  W6t,  512, 192, 192, 0};    // W6
    sa.t[1] = {d_in[9],  W7vt, 128, 192, 704, 512};  // W7 variable cols
    sa.t[2] = {d_in[10], W8t,  64, 128, 128, 0};     // W8
    sa.t[3] = {d_in[11], W9t,  128, 64, 64, 0};      // W9
    sa.t[4] = {d_in[5],  W3t,  64, 128, 128, 0};     // W3 transposed (prep/gridprep)
    sa.t[5] = {d_in[7],  W5t,  64, 128, 128, 0};     // W5 transposed
    k_setup<<<dim3(384, 35), 256, 0, stream>>>(sa, d_in[4], d_in[6], d_in[9],
                                               wf2, wf4, wf7, x, xgrid, flag,
                                               xt, gt, gT3, gn);

    const int PG = BN / 4;         // wave-per-point grids (2048)
    const int EW = BN * 64 / 256;  // elementwise grids
    const int CK = BN * K_;
    const int KNNG = BN / 16 + BM / 4;   // 512 nearest blocks + 256 nbr blocks

    // ---- stage A (D=3, W1,W2) ----
    k_pgrid3<<<BM / 4, 256, 0, stream>>>(gt, cW[0], Pg);
    k_knn3<<<KNNG, 256, 0, stream>>>(xt, gt, gT3, gn, Pg, nearest, nbr, T1b, T2b, Mnb, Mxb);
    k_prep_stats<3><<<PG, 256, 0, stream>>>(xt, cW[0], nearest, T1b, T2b, D0b, S0b, partials);
    k_redfin<2048, 64><<<32, 256, 0, stream>>>(partials, redbuf, counters + 0, CK, cG[0], cB[0], prm + 0 * 1024);
    k_pass1_mfma<<<BN / 2, 256, 0, stream>>>(Pg, D0b, S0b, nearest, nbr, prm + 0 * 1024, wf2, partials, mnb, mxb);
    k_redfin<4096, 64><<<32, 256, 0, stream>>>(partials, redbuf, counters + 1, CK, cG[1], cB[1], prm + 1 * 1024);
    k_apply<<<EW, 256, 0, stream>>>(mnb, mxb, prm + 1 * 1024, x1t);

    // ---- stage B (D=64, W3,W4) ----
    k_gridprep<<<BM / 4, 256, 0, stream>>>(x1t, FPS, W3t, x1gt, gT64, gn, Pg);
    k_knn64<<<KNNG, 256, 0, stream>>>(x1t, x1gt, gT64, gn, Pg, nearest, nbr, T1b, T2b, Mnb, Mxb);
    k_prep_stats<64><<<PG, 256, 0, stream>>>(x1t, W3t, nearest, T1b, T2b, D0b, S0b, partials);
    k_redfin<2048, 64><<<32, 256, 0, stream>>>(partials, redbuf, counters + 2, CK, cG[2], cB[2], prm + 2 * 1024);
    k_pass1_mfma<<<BN / 2, 256, 0, stream>>>(Pg, D0b, S0b, nearest, nbr, prm + 2 * 1024, wf4, partials, mnb, mxb);
    k_redfin<4096, 64><<<32, 256, 0, stream>>>(partials, redbuf, counters + 3, CK, cG[3], cB[3], prm + 3 * 1024);
    k_apply<<<EW, 256, 0, stream>>>(mnb, mxb, prm + 3 * 1024, x2t);

    // ---- stage C (D=64, W5 single conv) ----
    k_gridprep<<<BM / 4, 256, 0, stream>>>(x2t, FPS, W5t, x2gt, gT64, gn, Pg);
    k_knn64<<<KNNG, 256, 0, stream>>>(x2t, x2gt, gT64, gn, Pg, nearest, nbr, T1b, T2b, Mnb, Mxb);
    k_prep_stats<64><<<PG, 256, 0, stream>>>(x2t, W5t, nearest, T1b, T2b, D0b, S0b, partials);
    k_redfin<2048, 64><<<32, 256, 0, stream>>>(partials, redbuf, counters + 4, CK, cG[4], cB[4], prm + 4 * 1024);
    k_apply0<<<EW, 256, 0, stream>>>(D0b, S0b, nearest, Mnb, Mxb, prm + 4 * 1024, x3t);

    // ---- global MLP tail ----
    k_conv_w6<<<BM / 4, 256, 0, stream>>>(x1gt, x2gt, x3t, FPS, W6t, y6, partials);
    k_redfin<256, 512><<<32, 256, 0, stream>>>(partials, redbuf, counters + 5, BM, cG[5], cB[5], prm + 5 * 1024);
    k_maxM<<<B_ * 64, 256, 0, stream>>>(y6, prm + 5 * 1024, xgmax);
    k_p7<<<64, 256, 0, stream>>>(xgmax, cW[6], p7);
    k_conv_w7m<<<BN / 16, 256, 0, stream>>>(x1t, x2t, x3t, p7, wf7, y7, partials);
    k_redfin<512, 128><<<32, 256, 0, stream>>>(partials, redbuf, counters + 6, BN, cG[6], cB[6], prm + 6 * 1024);
    k_conv_w8<<<BN / 4, 256, 0, stream>>>(y7, prm + 6 * 1024, W8t, y8, partials);
    k_redfin<2048, 64><<<32, 256, 0, stream>>>(partials, redbuf, counters + 7, BN, cG[7], cB[7], prm + 7 * 1024);
    k_final<<<BN / 2, 256, 0, stream>>>(y8, prm + 7 * 1024, W9t, d_out, flag);
}